// Round 7
// baseline (391.306 us; speedup 1.0000x reference)
//
#include <hip/hip_runtime.h>
#include <hip/hip_bf16.h>
#include <hip/hip_fp16.h>

// Problem constants
#define N_NODES 10000
#define N_EDGES 128000
constexpr int C = 128;
constexpr int A = 10;

constexpr float INV_SQRT_C  = 0.08838834764831845f;   // 1/sqrt(128)
constexpr float INV_SQRT_R  = 0.35355339059327373f;   // 1/sqrt(8)
constexpr float INV_SQRT_64 = 0.125f;                 // 1/sqrt(64)
constexpr float INV_SQRT_CA = 0.027950849718747374f;  // 1/sqrt(1280)
constexpr float INV_SQRT_2C = 0.0625f;                // 1/sqrt(256)
constexpr float INV_SQRT_3  = 0.57735026918962576f;

typedef short short8 __attribute__((ext_vector_type(8)));
typedef _Float16 f16x8 __attribute__((ext_vector_type(8)));
typedef _Float16 f16x2 __attribute__((ext_vector_type(2)));
typedef float f32x4 __attribute__((ext_vector_type(4)));

__device__ __forceinline__ float silu_f(float x) { return x / (1.0f + __expf(-x)); }

__device__ __forceinline__ void atomic_add_f32(float* p, float v) {
  __hip_atomic_fetch_add(p, v, __ATOMIC_RELAXED, __HIP_MEMORY_SCOPE_AGENT);
}

__device__ __forceinline__ unsigned short f2h(float f) {
  return __builtin_bit_cast(unsigned short, (_Float16)f);  // RNE
}

__device__ __forceinline__ unsigned int pk2h(float a, float b) {
  auto h = __builtin_amdgcn_cvt_pkrtz(a, b);  // __fp16 ext_vector(2)
  return __builtin_bit_cast(unsigned int, h);
}

__device__ __forceinline__ unsigned int pkmul_h2(unsigned int x, unsigned int y) {
  const f16x2 a = __builtin_bit_cast(f16x2, x), b = __builtin_bit_cast(f16x2, y);
  return __builtin_bit_cast(unsigned int, a * b);  // v_pk_mul_f16
}

__device__ __forceinline__ float4 h4tof4(uint2 v) {
  const __half2 lo = __builtin_bit_cast(__half2, v.x);
  const __half2 hi = __builtin_bit_cast(__half2, v.y);
  const float2 flo = __half22float2(lo), fhi = __half22float2(hi);
  return make_float4(flo.x, flo.y, fhi.x, fhi.y);
}

// ---------------------------------------------------------------------------
// cvtw helper: weight (K x N fp32, row-major) -> f16 A-operand swizzle of W^T.
// ---------------------------------------------------------------------------
__device__ __forceinline__ void cvtw(const float* __restrict__ src,
                                     unsigned short* __restrict__ dst,
                                     int idx, int lgN, int KT) {
  const int k = idx >> lgN;
  const int n = idx & ((1 << lgN) - 1);
  dst[((n * KT + (k >> 5)) << 5) + (k & 31)] = f2h(src[idx]);
}

// ---------------------------------------------------------------------------
// k_prep_node (merged, R6-proven): node-up GEMM (blocks 0..1249) + weight
// converts / histogram (blocks 1250..2549).
// ---------------------------------------------------------------------------
__global__ __launch_bounds__(256) void k_prep_node(
    const float* __restrict__ nf, const float* __restrict__ Wu0,
    const float* __restrict__ Wu1, __half* __restrict__ Hh,
    const float* __restrict__ W0, const float* __restrict__ W1,
    unsigned short* __restrict__ B0, unsigned short* __restrict__ B1,
    const float* __restrict__ R1, unsigned short* __restrict__ R1a,
    const float* __restrict__ R2, unsigned short* __restrict__ R2a,
    const float* __restrict__ R3, unsigned short* __restrict__ R3a,
    const int* __restrict__ eidx, int* __restrict__ counts) {
  __shared__ __align__(16) float xs[8][C][4];  // node branch only
  const int bid = blockIdx.x, t = threadIdx.x;
  if (bid < 1250) {
    const int n0 = bid * 8;
    for (int idx = t; idx < 8 * 512; idx += 256) {
      const int nn = idx >> 9, q = idx & 511;
      const float val = nf[(size_t)(n0 + nn) * 512 + q];
      if (q < C) xs[nn][q][0] = val;
      else { const int r = q - C; xs[nn][r / 3][1 + r % 3] = val; }
    }
    __syncthreads();
    const int g = t >> 7, v = t & 127;
    float acc[4][4] = {};
    for (int u = 0; u < C; ++u) {
      const float w0 = Wu0[u * C + v];
      const float w1 = Wu1[u * C + v];
#pragma unroll
      for (int nn = 0; nn < 4; ++nn) {
        const float4 xv = *(const float4*)&xs[g * 4 + nn][u][0];
        acc[nn][0] = fmaf(xv.x, w0, acc[nn][0]);
        acc[nn][1] = fmaf(xv.y, w1, acc[nn][1]);
        acc[nn][2] = fmaf(xv.z, w1, acc[nn][2]);
        acc[nn][3] = fmaf(xv.w, w1, acc[nn][3]);
      }
    }
#pragma unroll
    for (int nn = 0; nn < 4; ++nn) {
      const int n = n0 + g * 4 + nn;
      uint2 o;
      o.x = pk2h(acc[nn][0] * INV_SQRT_C, acc[nn][1] * INV_SQRT_C);
      o.y = pk2h(acc[nn][2] * INV_SQRT_C, acc[nn][3] * INV_SQRT_C);
      *(uint2*)&Hh[(size_t)n * 512 + v * 4] = o;
    }
  } else {
    const int b = bid - 1250;
    if (b < 640) {
      // skip GEMM B operand: k = u*10+a -> permuted k' = a*128+u
      const int idx = b * 256 + t;
      const int k = idx >> 7, col = idx & 127;
      const int u = k / 10, a = k - u * 10;
      const int kp = a * 128 + u;
      const int dst = ((kp >> 5) * 128 + col) * 32 + (kp & 31);
      B0[dst] = f2h(W0[idx]);
      B1[dst] = f2h(W1[idx]);
    } else if (b < 656) {
      cvtw(R1, R1a, (b - 640) * 256 + t, 6, 2);
    } else if (b < 672) {
      cvtw(R2, R2a, (b - 656) * 256 + t, 6, 2);
    } else if (b < 800) {
      cvtw(R3, R3a, (b - 672) * 256 + t, 9, 2);
    } else {
      const int e = (b - 800) * 256 + t;
      if (e < N_EDGES) atomicAdd(&counts[eidx[N_EDGES + e]], 1);
    }
  }
}

// ---------------------------------------------------------------------------
// K2 v3 (barrier-free): sc as two f16 GEMMs, k' = a*128+u order.
// R5 ran 40 __syncthreads (one per K-step): zs repack was split across waves
// while every wave's MFMA read all 64 rows -> barrier-drain bound (~86k cyc
// vs ~1.5k MFMA). Now each wave repacks ALL 64 rows into its OWN buffer
// zsw[wave] (4x redundant pkmul, cheap) -> ZERO barriers in the K-loop;
// within-wave LDS write->read ordering is compiler-lgkmcnt-enforced (same
// mechanism as the mlp chunk loop, HW-proven in R2). XOR col swizzle
// ((row>>2)&3)<<3 with 96B row stride -> all b128 LDS ops <=2-way (free).
// LDS 44.5 KB -> 3 blocks/CU >= the 2.45 the 626-block grid needs.
// ---------------------------------------------------------------------------
__global__ __launch_bounds__(256) void k_skip_mfma(
    const float* __restrict__ nf, const float* __restrict__ attrs,
    const unsigned short* __restrict__ B0, const unsigned short* __restrict__ B1,
    float* __restrict__ out_sc) {
  __shared__ __align__(16) unsigned short xs[64][136];    // 17408 B
  __shared__ float at[64][10];                            // 2560 B
  __shared__ __align__(16) unsigned short zsw[4][64][48]; // 24576 B per-wave

  const int t = threadIdx.x;
  const int wave = t >> 6, lane = t & 63;
  const bool isG0 = blockIdx.x < 157;
  const int r0 = isG0 ? blockIdx.x * 64 : (blockIdx.x - 157) * 64;
  const int rcount = isG0 ? 10000 : 30000;
  const unsigned short* __restrict__ Bsw = isG0 ? B0 : B1;

  for (int idx = t; idx < 64 * 128; idx += 256) {
    const int i = idx >> 7, u = idx & 127;
    const int r = r0 + i;
    float v = 0.f;
    if (r < rcount) {
      if (isG0) v = nf[(size_t)r * 512 + u];
      else {
        const int n = r / 3, kc = r - n * 3;
        v = nf[(size_t)n * 512 + 128 + u * 3 + kc];
      }
    }
    xs[i][u] = f2h(v);
  }
  for (int idx = t; idx < 640; idx += 256) {
    const int i = idx / 10, a = idx - (idx / 10) * 10;
    const int r = r0 + i;
    float v = 0.f;
    if (r < rcount) v = attrs[(size_t)(isG0 ? r : r / 3) * 10 + a];
    at[i][a] = v;
  }
  __syncthreads();  // the ONLY barrier

  const int m = lane & 15, q = lane >> 4;
  const int colB = wave * 32;
  unsigned short (*zw)[48] = zsw[wave];
  const int wr_key = ((lane >> 2) & 3) << 3;  // XOR key for writes (row=lane)
  const int rd_key = ((m >> 2) & 3) << 3;     // == key(rt*16+m) for all rt

  // attr row `lane` -> 10 half2-broadcast registers (compile-time indexed)
  unsigned int atr2[10];
#pragma unroll
  for (int a = 0; a < 10; ++a) {
    const unsigned int h = f2h(at[lane][a]);
    atr2[a] = h | (h << 16);
  }

  f32x4 acc[4][2];
#pragma unroll
  for (int rt = 0; rt < 4; ++rt)
#pragma unroll
    for (int ct = 0; ct < 2; ++ct) acc[rt][ct] = (f32x4){0.f, 0.f, 0.f, 0.f};

#pragma unroll
  for (int a = 0; a < 10; ++a) {
    const unsigned int av2 = atr2[a];
#pragma unroll
    for (int kk = 0; kk < 4; ++kk) {
      const int kt = a * 4 + kk;
      // B fragments (global, L2-resident) -- issued early, vmcnt-hidden
      f16x8 bfrag[2];
#pragma unroll
      for (int ct = 0; ct < 2; ++ct) {
        const unsigned short* bp =
            &Bsw[(size_t)(kt * 128 + colB + ct * 16 + m) * 32 + q * 8];
        bfrag[ct] = *(const f16x8*)bp;
      }
      // repack row `lane`, u-window kk*32..+32 into this wave's own buffer.
      // xv0 = halves 0..15 of the window, xv1 = halves 16..31.
      {
        const uint4 xv0 = *(const uint4*)&xs[lane][kk * 32];
        const uint4 xv1 = *(const uint4*)&xs[lane][kk * 32 + 8];
        const uint4 xv2 = *(const uint4*)&xs[lane][kk * 32 + 16];
        const uint4 xv3 = *(const uint4*)&xs[lane][kk * 32 + 24];
        uint4 z;
        z.x = pkmul_h2(xv0.x, av2); z.y = pkmul_h2(xv0.y, av2);
        z.z = pkmul_h2(xv0.z, av2); z.w = pkmul_h2(xv0.w, av2);
        *(uint4*)&zw[lane][0 ^ wr_key] = z;    // halves 0..7
        z.x = pkmul_h2(xv1.x, av2); z.y = pkmul_h2(xv1.y, av2);
        z.z = pkmul_h2(xv1.z, av2); z.w = pkmul_h2(xv1.w, av2);
        *(uint4*)&zw[lane][8 ^ wr_key] = z;    // halves 8..15
        z.x = pkmul_h2(xv2.x, av2); z.y = pkmul_h2(xv2.y, av2);
        z.z = pkmul_h2(xv2.z, av2); z.w = pkmul_h2(xv2.w, av2);
        *(uint4*)&zw[lane][16 ^ wr_key] = z;   // halves 16..23
        z.x = pkmul_h2(xv3.x, av2); z.y = pkmul_h2(xv3.y, av2);
        z.z = pkmul_h2(xv3.z, av2); z.w = pkmul_h2(xv3.w, av2);
        *(uint4*)&zw[lane][24 ^ wr_key] = z;   // halves 24..31
      }
#pragma unroll
      for (int rt = 0; rt < 4; ++rt) {
        const f16x8 afrag =
            *(const f16x8*)&zw[rt * 16 + m][(q * 8) ^ rd_key];
#pragma unroll
        for (int ct = 0; ct < 2; ++ct)
          acc[rt][ct] = __builtin_amdgcn_mfma_f32_16x16x32_f16(
              afrag, bfrag[ct], acc[rt][ct], 0, 0, 0);
      }
    }
  }

#pragma unroll
  for (int rt = 0; rt < 4; ++rt) {
#pragma unroll
    for (int reg = 0; reg < 4; ++reg) {
      const int rloc = rt * 16 + q * 4 + reg;
      const int r = r0 + rloc;
      if (r < rcount) {
#pragma unroll
        for (int ct = 0; ct < 2; ++ct) {
          const int v = colB + ct * 16 + m;
          const float val = acc[rt][ct][reg] * INV_SQRT_CA;
          if (isG0) {
            out_sc[(size_t)r * 512 + v] = val;
          } else {
            const int n = r / 3, kc = r - (r / 3) * 3;
            out_sc[(size_t)n * 512 + 128 + v * 3 + kc] = val;
          }
        }
      }
    }
  }
}

// ---------------------------------------------------------------------------
// Sort-by-receiver: scan -> scatter (histogram lives in k_prep_node)
// ---------------------------------------------------------------------------
__global__ __launch_bounds__(1024) void k_scan(const int* __restrict__ counts,
                                               int* __restrict__ offsets,
                                               int* __restrict__ cursor) {
  __shared__ int part[1024];
  const int t = threadIdx.x;
  int local[10];
  int s = 0;
#pragma unroll
  for (int i = 0; i < 10; ++i) {
    const int idx = t * 10 + i;
    const int c = (idx < N_NODES) ? counts[idx] : 0;
    local[i] = s;
    s += c;
  }
  part[t] = s;
  __syncthreads();
  for (int off = 1; off < 1024; off <<= 1) {
    const int add = (t >= off) ? part[t - off] : 0;
    __syncthreads();
    part[t] += add;
    __syncthreads();
  }
  const int pre = (t > 0) ? part[t - 1] : 0;
#pragma unroll
  for (int i = 0; i < 10; ++i) {
    const int idx = t * 10 + i;
    if (idx < N_NODES) {
      const int o = pre + local[i];
      offsets[idx] = o;
      cursor[idx] = o;
    }
  }
  if (t == 1023) offsets[N_NODES] = part[1023];
}

__global__ __launch_bounds__(256) void k_scatter(
    const int* __restrict__ eidx, const float* __restrict__ ea_g,
    const float* __restrict__ ef_g,
    int* __restrict__ cursor,
    int* __restrict__ snd_s, int* __restrict__ rcv_s,
    float* __restrict__ ea_s, float* __restrict__ ef_s) {
  const int e = blockIdx.x * 256 + threadIdx.x;
  if (e < N_EDGES) {
    const int r = eidx[N_EDGES + e];
    const int pos = atomicAdd(&cursor[r], 1);
    snd_s[pos] = eidx[e];
    rcv_s[pos] = r;
    ((float4*)ea_s)[pos] = ((const float4*)ea_g)[e];
    ((float4*)ef_s)[pos * 2]     = ((const float4*)ef_g)[e * 2];
    ((float4*)ef_s)[pos * 2 + 1] = ((const float4*)ef_g)[e * 2 + 1];
  }
}

// ---------------------------------------------------------------------------
// K3 (R5-proven, standalone again): edge MLP + messages + segmented reduce.
// ---------------------------------------------------------------------------
__global__ __launch_bounds__(256, 4) void k_mlp_msg(
    const float* __restrict__ ef_s, const float* __restrict__ ea_s,
    const int* __restrict__ snd_s, const int* __restrict__ rcv_s,
    const int* __restrict__ offsets,
    const float* __restrict__ R0, const unsigned short* __restrict__ R1a,
    const unsigned short* __restrict__ R2a, const unsigned short* __restrict__ R3a,
    const float* __restrict__ Wd, const __half* __restrict__ Hh,
    float* __restrict__ M, float* __restrict__ density) {
  __shared__ __align__(16) unsigned short actA[128][72];  // 18 KB
  __shared__ __align__(16) unsigned char uni[18432];      // 18 KB union
  __shared__ __align__(16) float ys[128][4];              // 2 KB
  __shared__ __align__(16) int sn[144];                   // 576 B
  __shared__ __align__(16) int rc[128];                   // 512 B
  float (*efs)[9] = (float (*)[9]) & uni[0];
  unsigned short (*actB)[72] = (unsigned short (*)[72]) & uni[0];
  __half (*wls2)[536] = (__half (*)[536]) & uni[0];

  const int t = threadIdx.x;
  const int wave = t >> 6, lane = t & 63, m = lane & 15, q = lane >> 4;
  const int e0 = blockIdx.x * 128;

  {
    const float4 v = *(const float4*)&ef_s[(size_t)e0 * 8 + t * 4];
    const int e = t >> 1, c0 = (t & 1) * 4;
    efs[e][c0] = v.x; efs[e][c0 + 1] = v.y;
    efs[e][c0 + 2] = v.z; efs[e][c0 + 3] = v.w;
  }
  if (t < 128) {
    *(float4*)&ys[t][0] = ((const float4*)ea_s)[e0 + t];
    sn[t] = snd_s[e0 + t];
    rc[t] = rcv_s[e0 + t];
  } else if (t < 144) {
    sn[t] = 0;
  }
  __syncthreads();

  const int u = t & 127, half = t >> 7;
  const size_t ucol = (size_t)(u << 2);
  uint2 hA[4], hB[4];
#pragma unroll
  for (int j = 0; j < 4; ++j)
    hA[j] = *(const uint2*)&Hh[(size_t)sn[j] * 512 + ucol];
#pragma unroll
  for (int j = 0; j < 4; ++j)
    hB[j] = *(const uint2*)&Hh[(size_t)sn[4 + j] * 512 + ucol];

  if (t < 128) {
    float s = 0.f;
#pragma unroll
    for (int i = 0; i < 8; ++i) s = fmaf(efs[t][i], Wd[i], s);
    s *= INV_SQRT_R;
    atomic_add_f32(&density[rc[t]], tanhf(s * s));
  }

  // L1
  {
    const int e = t & 127, j0 = (t >> 7) * 32;
    float a[32] = {};
#pragma unroll
    for (int i = 0; i < 8; ++i) {
      const float v = efs[e][i];
#pragma unroll
      for (int jj = 0; jj < 32; ++jj)
        a[jj] = fmaf(v, R0[i * 64 + j0 + jj], a[jj]);
    }
#pragma unroll
    for (int g = 0; g < 8; ++g) {
      uint2 pk;
      pk.x = pk2h(silu_f(a[4 * g] * INV_SQRT_R), silu_f(a[4 * g + 1] * INV_SQRT_R));
      pk.y = pk2h(silu_f(a[4 * g + 2] * INV_SQRT_R), silu_f(a[4 * g + 3] * INV_SQRT_R));
      *(uint2*)&actA[e][j0 + g * 4] = pk;
    }
  }
  __syncthreads();

  // L2
  {
    const f16x8 af0 = *(const f16x8*)&R1a[(((wave * 16 + m) * 2 + 0) << 5) + q * 8];
    const f16x8 af1 = *(const f16x8*)&R1a[(((wave * 16 + m) * 2 + 1) << 5) + q * 8];
#pragma unroll
    for (int et = 0; et < 8; ++et) {
      const f16x8 bf0 = *(const f16x8*)&actA[et * 16 + m][q * 8];
      const f16x8 bf1 = *(const f16x8*)&actA[et * 16 + m][32 + q * 8];
      f32x4 c = {0.f, 0.f, 0.f, 0.f};
      c = __builtin_amdgcn_mfma_f32_16x16x32_f16(af0, bf0, c, 0, 0, 0);
      c = __builtin_amdgcn_mfma_f32_16x16x32_f16(af1, bf1, c, 0, 0, 0);
      uint2 pk;
      pk.x = pk2h(silu_f(c[0] * INV_SQRT_64), silu_f(c[1] * INV_SQRT_64));
      pk.y = pk2h(silu_f(c[2] * INV_SQRT_64), silu_f(c[3] * INV_SQRT_64));
      *(uint2*)&actB[et * 16 + m][wave * 16 + q * 4] = pk;
    }
  }
  __syncthreads();

  // L3
  {
    const f16x8 af0 = *(const f16x8*)&R2a[(((wave * 16 + m) * 2 + 0) << 5) + q * 8];
    const f16x8 af1 = *(const f16x8*)&R2a[(((wave * 16 + m) * 2 + 1) << 5) + q * 8];
#pragma unroll
    for (int et = 0; et < 8; ++et) {
      const f16x8 bf0 = *(const f16x8*)&actB[et * 16 + m][q * 8];
      const f16x8 bf1 = *(const f16x8*)&actB[et * 16 + m][32 + q * 8];
      f32x4 c = {0.f, 0.f, 0.f, 0.f};
      c = __builtin_amdgcn_mfma_f32_16x16x32_f16(af0, bf0, c, 0, 0, 0);
      c = __builtin_amdgcn_mfma_f32_16x16x32_f16(af1, bf1, c, 0, 0, 0);
      uint2 pk;
      pk.x = pk2h(silu_f(c[0] * INV_SQRT_64), silu_f(c[1] * INV_SQRT_64));
      pk.y = pk2h(silu_f(c[2] * INV_SQRT_64), silu_f(c[3] * INV_SQRT_64));
      *(uint2*)&actA[et * 16 + m][wave * 16 + q * 4] = pk;
    }
  }
  __syncthreads();

  const int baseJ = (wave & 1) * 4 + (wave >> 1) * 16;
  f16x8 afL[4][2], afH[4][2];
#pragma unroll
  for (int i = 0; i < 4; ++i) {
#pragma unroll
    for (int kt = 0; kt < 2; ++kt) {
      const int JL = baseJ + i, JH = JL + 8;
      afL[i][kt] = *(const f16x8*)&R3a[(((JL * 16 + m) * 2 + kt) << 5) + q * 8];
      afH[i][kt] = *(const f16x8*)&R3a[(((JH * 16 + m) * 2 + kt) << 5) + q * 8];
    }
  }

  float a0 = 0.f, a1 = 0.f, a2 = 0.f, a3 = 0.f;
  int cur = rc[0];
  int s0c = offsets[cur], s1c = offsets[cur + 1];
  const int colx = (half ? 128 + u : u) * 2;

  auto flush = [&](int n, int s0, int s1) {
    float* Mp = &M[(size_t)n * 1024 + (half << 9) + (u << 2)];
    if (s0 >= e0 && s1 <= e0 + 128) {
      *(float4*)Mp = make_float4(a0, a1, a2, a3);
    } else {
      atomic_add_f32(Mp + 0, a0);
      atomic_add_f32(Mp + 1, a1);
      atomic_add_f32(Mp + 2, a2);
      atomic_add_f32(Mp + 3, a3);
    }
  };

  auto proc = [&](const uint2 hcur, unsigned int pr, const float4 yv, int n) {
    if (n != cur) {  // wave-uniform
      flush(cur, s0c, s1c);
      a0 = a1 = a2 = a3 = 0.f;
      cur = n;
      s0c = offsets[n];
      s1c = offsets[n + 1];
    }
    const float4 h4 = h4tof4(hcur);
    const __half2 ph = __builtin_bit_cast(__half2, pr);
    const float2 pw = __half22float2(ph);
    if (half == 0) {
      a0 = fmaf(pw.x * h4.x, yv.x, a0);
      const float c1 = pw.y * h4.x;
      a1 = fmaf(c1, yv.y, a1);
      a2 = fmaf(c1, yv.z, a2);
      a3 = fmaf(c1, yv.w, a3);
    } else {
      const float dt = h4.y * yv.y + h4.z * yv.z + h4.w * yv.w;
      a0 = fmaf(pw.y * dt, INV_SQRT_3, a0);
      const float c3 = pw.x * yv.x;
      a1 = fmaf(c3, h4.y, a1);
      a2 = fmaf(c3, h4.z, a2);
      a3 = fmaf(c3, h4.w, a3);
    }
  };

#define MSG_GROUP(G, HX)                                                    \
  {                                                                         \
    const int gb = ch * 16 + (G) * 4;                                       \
    unsigned int prv[4];                                                    \
    float4 yv4[4];                                                          \
    _Pragma("unroll") for (int j = 0; j < 4; ++j)                           \
        prv[j] = *(const unsigned int*)&wls2[(G) * 4 + j][colx];            \
    _Pragma("unroll") for (int j = 0; j < 4; ++j)                           \
        yv4[j] = *(const float4*)&ys[gb + j][0];                            \
    const int4 rc4 = *(const int4*)&rc[gb];                                 \
    proc(HX[0], prv[0], yv4[0], rc4.x);                                     \
    proc(HX[1], prv[1], yv4[1], rc4.y);                                     \
    proc(HX[2], prv[2], yv4[2], rc4.z);                                     \
    proc(HX[3], prv[3], yv4[3], rc4.w);                                     \
    const int4 sn4 = *(const int4*)&sn[gb + 8];                             \
    HX[0] = *(const uint2*)&Hh[(size_t)sn4.x * 512 + ucol];                 \
    HX[1] = *(const uint2*)&Hh[(size_t)sn4.y * 512 + ucol];                 \
    HX[2] = *(const uint2*)&Hh[(size_t)sn4.z * 512 + ucol];                 \
    HX[3] = *(const uint2*)&Hh[(size_t)sn4.w * 512 + ucol];                 \
  }

  // BARRIER-FREE chunk loop (wave w produces AND consumes wls2 [w*64,(w+1)*64))
#pragma unroll 1
  for (int ch = 0; ch < 8; ++ch) {
    {
      const f16x8 bf0 = *(const f16x8*)&actA[ch * 16 + m][q * 8];
      const f16x8 bf1 = *(const f16x8*)&actA[ch * 16 + m][32 + q * 8];
#pragma unroll
      for (int i = 0; i < 4; ++i) {
        f32x4 cL = {0.f, 0.f, 0.f, 0.f}, cH = {0.f, 0.f, 0.f, 0.f};
        cL = __builtin_amdgcn_mfma_f32_16x16x32_f16(afL[i][0], bf0, cL, 0, 0, 0);
        cL = __builtin_amdgcn_mfma_f32_16x16x32_f16(afL[i][1], bf1, cL, 0, 0, 0);
        cH = __builtin_amdgcn_mfma_f32_16x16x32_f16(afH[i][0], bf0, cH, 0, 0, 0);
        cH = __builtin_amdgcn_mfma_f32_16x16x32_f16(afH[i][1], bf1, cH, 0, 0, 0);
        uint4 pk;
        pk.x = pk2h(cL[0] * INV_SQRT_64, cH[0] * INV_SQRT_64);
        pk.y = pk2h(cL[1] * INV_SQRT_64, cH[1] * INV_SQRT_64);
        pk.z = pk2h(cL[2] * INV_SQRT_64, cH[2] * INV_SQRT_64);
        pk.w = pk2h(cL[3] * INV_SQRT_64, cH[3] * INV_SQRT_64);
        const int JL = baseJ + i;
        const int pidx0 = ((JL < 8) ? JL * 16 : (JL - 16) * 16 + 128) + q * 4;
        *(uint4*)&wls2[m][pidx0 * 2] = pk;
      }
    }
    MSG_GROUP(0, hA)
    MSG_GROUP(1, hB)
    MSG_GROUP(2, hA)
    MSG_GROUP(3, hB)
  }
#undef MSG_GROUP
  flush(cur, s0c, s1c);
}

// ---------------------------------------------------------------------------
// K5: out0 = M0 @ Wl0 /16/denom; out1[.,.,k] = M1[...,k] @ Wl1 /16/denom
// ---------------------------------------------------------------------------
__global__ __launch_bounds__(256) void k_out(
    const float* __restrict__ M, const float* __restrict__ density,
    const float* __restrict__ Wl0, const float* __restrict__ Wl1,
    float* __restrict__ out) {
  __shared__ __align__(16) float Ms[8][256][4];  // 32 KB
  __shared__ float dens[8];
  const int t = threadIdx.x;
  const int n0 = blockIdx.x * 8;
  const float4* Msrc = (const float4*)&M[(size_t)n0 * 1024];
  float4* Mdst = (float4*)&Ms[0][0][0];
  for (int idx = t; idx < 8 * 256; idx += 256) Mdst[idx] = Msrc[idx];
  if (t < 8) dens[t] = density[n0 + t] + 1.0f;
  __syncthreads();
  const int g = t >> 7, v = t & 127;
  float acc[4][4] = {};
  for (int p0 = 0; p0 < 256; p0 += 4) {
    float4 mv[4][4];
#pragma unroll
    for (int nn = 0; nn < 4; ++nn)
#pragma unroll
      for (int j = 0; j < 4; ++j)
        mv[nn][j] = *(const float4*)&Ms[g * 4 + nn][p0 + j][0];
#pragma unroll
    for (int j = 0; j < 4; ++j) {
      const float w0 = Wl0[(p0 + j) * C + v];
      const float w1 = Wl1[(p0 + j) * C + v];
#pragma unroll
      for (int nn = 0; nn < 4; ++nn) {
        acc[nn][0] = fmaf(mv[nn][j].x, w0, acc[nn][0]);
        acc[nn][1] = fmaf(mv[nn][j].y, w1, acc[nn][1]);
        acc[nn][2] = fmaf(mv[nn][j].z, w1, acc[nn][2]);
        acc[nn][3] = fmaf(mv[nn][j].w, w1, acc[nn][3]);
      }
    }
  }
#pragma unroll
  for (int nn = 0; nn < 4; ++nn) {
    const int n = n0 + g * 4 + nn;
    const float sc = INV_SQRT_2C / dens[g * 4 + nn];
    float4 o;
    o.x = acc[nn][0] * sc; o.y = acc[nn][1] * sc;
    o.z = acc[nn][2] * sc; o.w = acc[nn][3] * sc;
    *(float4*)&out[(size_t)n * 512 + v * 4] = o;
  }
}

// ---------------------------------------------------------------------------
extern "C" void kernel_launch(void* const* d_in, const int* in_sizes, int n_in,
                              void* d_out, int out_size, void* d_ws, size_t ws_size,
                              hipStream_t stream) {
  const float* node_attrs = (const float*)d_in[0];
  const float* node_feats = (const float*)d_in[1];
  const float* edge_attrs = (const float*)d_in[2];
  const float* edge_feats = (const float*)d_in[3];
  const int*   edge_index = (const int*)d_in[4];
  const float* W_up0 = (const float*)d_in[5];
  const float* W_up1 = (const float*)d_in[6];
  const float* R0 = (const float*)d_in[7];
  const float* R1 = (const float*)d_in[8];
  const float* R2 = (const float*)d_in[9];
  const float* R3 = (const float*)d_in[10];
  const float* Wd  = (const float*)d_in[11];
  const float* Wl0 = (const float*)d_in[12];
  const float* Wl1 = (const float*)d_in[13];
  const float* Ws0 = (const float*)d_in[14];
  const float* Ws1 = (const float*)d_in[15];
  float* out = (float*)d_out;

  __half* Hh = (__half*)d_ws;
  float* M = (float*)d_ws + (size_t)N_NODES * 512;
  float* density = M + (size_t)N_NODES * 1024;
  int* counts  = (int*)(density + 10000);
  int* offsets = counts + 10016;
  int* cursor  = offsets + 10016;
  int* snd_s   = cursor + 10016;
  int* rcv_s   = snd_s + N_EDGES;
  float* ea_s  = (float*)(rcv_s + N_EDGES);
  unsigned short* Bsw0 = (unsigned short*)(ea_s + (size_t)N_EDGES * 4);
  unsigned short* Bsw1 = Bsw0 + 1280 * 128;
  unsigned short* R1a  = Bsw1 + 1280 * 128;
  unsigned short* R2a  = R1a + 64 * 64;
  unsigned short* R3a  = R2a + 64 * 64;
  float* ef_s  = (float*)(R3a + 64 * 512);

  hipMemsetAsync(M, 0, ((size_t)N_NODES * 1024 + 10000 + 10016) * sizeof(float),
                 stream);

  k_prep_node<<<2550, 256, 0, stream>>>(node_feats, W_up0, W_up1, Hh, Ws0, Ws1,
                                        Bsw0, Bsw1, R1, R1a, R2, R2a, R3, R3a,
                                        edge_index, counts);
  k_scan<<<1, 1024, 0, stream>>>(counts, offsets, cursor);
  k_scatter<<<(N_EDGES + 255) / 256, 256, 0, stream>>>(
      edge_index, edge_attrs, edge_feats, cursor, snd_s, rcv_s, ea_s, ef_s);
  k_mlp_msg<<<N_EDGES / 128, 256, 0, stream>>>(ef_s, ea_s, snd_s, rcv_s,
                                               offsets, R0, R1a, R2a, R3a, Wd,
                                               Hh, M, density);
  k_out<<<N_NODES / 8, 256, 0, stream>>>(M, density, Wl0, Wl1, out);
  k_skip_mfma<<<157 + 469, 256, 0, stream>>>(node_feats, node_attrs, Bsw0, Bsw1,
                                             out + (size_t)N_NODES * 512);
}

// Round 8
// 318.879 us; speedup vs baseline: 1.2271x; 1.2271x over previous
//
#include <hip/hip_runtime.h>
#include <hip/hip_bf16.h>
#include <hip/hip_fp16.h>

// Problem constants
#define N_NODES 10000
#define N_EDGES 128000
constexpr int C = 128;
constexpr int A = 10;

constexpr float INV_SQRT_C  = 0.08838834764831845f;   // 1/sqrt(128)
constexpr float INV_SQRT_R  = 0.35355339059327373f;   // 1/sqrt(8)
constexpr float INV_SQRT_64 = 0.125f;                 // 1/sqrt(64)
constexpr float INV_SQRT_CA = 0.027950849718747374f;  // 1/sqrt(1280)
constexpr float INV_SQRT_2C = 0.0625f;                // 1/sqrt(256)
constexpr float INV_SQRT_3  = 0.57735026918962576f;

typedef short short8 __attribute__((ext_vector_type(8)));
typedef _Float16 f16x8 __attribute__((ext_vector_type(8)));
typedef _Float16 f16x2 __attribute__((ext_vector_type(2)));
typedef float f32x4 __attribute__((ext_vector_type(4)));

__device__ __forceinline__ float silu_f(float x) { return x / (1.0f + __expf(-x)); }

__device__ __forceinline__ void atomic_add_f32(float* p, float v) {
  __hip_atomic_fetch_add(p, v, __ATOMIC_RELAXED, __HIP_MEMORY_SCOPE_AGENT);
}

__device__ __forceinline__ unsigned short f2h(float f) {
  return __builtin_bit_cast(unsigned short, (_Float16)f);  // RNE
}

__device__ __forceinline__ unsigned int pk2h(float a, float b) {
  auto h = __builtin_amdgcn_cvt_pkrtz(a, b);  // __fp16 ext_vector(2)
  return __builtin_bit_cast(unsigned int, h);
}

__device__ __forceinline__ unsigned int pkmul_h2(unsigned int x, unsigned int y) {
  const f16x2 a = __builtin_bit_cast(f16x2, x), b = __builtin_bit_cast(f16x2, y);
  return __builtin_bit_cast(unsigned int, a * b);  // v_pk_mul_f16
}

__device__ __forceinline__ float4 h4tof4(uint2 v) {
  const __half2 lo = __builtin_bit_cast(__half2, v.x);
  const __half2 hi = __builtin_bit_cast(__half2, v.y);
  const float2 flo = __half22float2(lo), fhi = __half22float2(hi);
  return make_float4(flo.x, flo.y, fhi.x, fhi.y);
}

// ---------------------------------------------------------------------------
// cvtw helper: weight (K x N fp32, row-major) -> f16 A-operand swizzle of W^T.
// ---------------------------------------------------------------------------
__device__ __forceinline__ void cvtw(const float* __restrict__ src,
                                     unsigned short* __restrict__ dst,
                                     int idx, int lgN, int KT) {
  const int k = idx >> lgN;
  const int n = idx & ((1 << lgN) - 1);
  dst[((n * KT + (k >> 5)) << 5) + (k & 31)] = f2h(src[idx]);
}

// ---------------------------------------------------------------------------
// k_prep_node (merged, R6-proven): node-up GEMM (blocks 0..1249) + weight
// converts / histogram (blocks 1250..2549).
// ---------------------------------------------------------------------------
__global__ __launch_bounds__(256) void k_prep_node(
    const float* __restrict__ nf, const float* __restrict__ Wu0,
    const float* __restrict__ Wu1, __half* __restrict__ Hh,
    const float* __restrict__ W0, const float* __restrict__ W1,
    unsigned short* __restrict__ B0, unsigned short* __restrict__ B1,
    const float* __restrict__ R1, unsigned short* __restrict__ R1a,
    const float* __restrict__ R2, unsigned short* __restrict__ R2a,
    const float* __restrict__ R3, unsigned short* __restrict__ R3a,
    const int* __restrict__ eidx, int* __restrict__ counts) {
  __shared__ __align__(16) float xs[8][C][4];  // node branch only
  const int bid = blockIdx.x, t = threadIdx.x;
  if (bid < 1250) {
    const int n0 = bid * 8;
    for (int idx = t; idx < 8 * 512; idx += 256) {
      const int nn = idx >> 9, q = idx & 511;
      const float val = nf[(size_t)(n0 + nn) * 512 + q];
      if (q < C) xs[nn][q][0] = val;
      else { const int r = q - C; xs[nn][r / 3][1 + r % 3] = val; }
    }
    __syncthreads();
    const int g = t >> 7, v = t & 127;
    float acc[4][4] = {};
    for (int u = 0; u < C; ++u) {
      const float w0 = Wu0[u * C + v];
      const float w1 = Wu1[u * C + v];
#pragma unroll
      for (int nn = 0; nn < 4; ++nn) {
        const float4 xv = *(const float4*)&xs[g * 4 + nn][u][0];
        acc[nn][0] = fmaf(xv.x, w0, acc[nn][0]);
        acc[nn][1] = fmaf(xv.y, w1, acc[nn][1]);
        acc[nn][2] = fmaf(xv.z, w1, acc[nn][2]);
        acc[nn][3] = fmaf(xv.w, w1, acc[nn][3]);
      }
    }
#pragma unroll
    for (int nn = 0; nn < 4; ++nn) {
      const int n = n0 + g * 4 + nn;
      uint2 o;
      o.x = pk2h(acc[nn][0] * INV_SQRT_C, acc[nn][1] * INV_SQRT_C);
      o.y = pk2h(acc[nn][2] * INV_SQRT_C, acc[nn][3] * INV_SQRT_C);
      *(uint2*)&Hh[(size_t)n * 512 + v * 4] = o;
    }
  } else {
    const int b = bid - 1250;
    if (b < 640) {
      // skip GEMM B operand: k = u*10+a -> permuted k' = a*128+u
      const int idx = b * 256 + t;
      const int k = idx >> 7, col = idx & 127;
      const int u = k / 10, a = k - u * 10;
      const int kp = a * 128 + u;
      const int dst = ((kp >> 5) * 128 + col) * 32 + (kp & 31);
      B0[dst] = f2h(W0[idx]);
      B1[dst] = f2h(W1[idx]);
    } else if (b < 656) {
      cvtw(R1, R1a, (b - 640) * 256 + t, 6, 2);
    } else if (b < 672) {
      cvtw(R2, R2a, (b - 656) * 256 + t, 6, 2);
    } else if (b < 800) {
      cvtw(R3, R3a, (b - 672) * 256 + t, 9, 2);
    } else {
      const int e = (b - 800) * 256 + t;
      if (e < N_EDGES) atomicAdd(&counts[eidx[N_EDGES + e]], 1);
    }
  }
}

// ---------------------------------------------------------------------------
// K2 v4: R5's PROVEN structure (same zs row layout/stride-80B -> known-good
// bank profile; same 1-barrier-per-phase double-buffer) with two minimal
// deltas (R7's barrier-free rewrite regressed: 8.8M bank conflicts, VGPR
// 140 -- reverted):
//  * 2 K-steps per phase -> 20 barriers instead of 40. zs[2][2][64][40]
//    (20.5 KB; total 40.4 KB -> 4 blocks/CU).
//  * bfrag cross-phase prefetch: phase p issues phase p+1's 4 global b128
//    loads right after the barrier, consumed next phase -> L2 latency
//    (~200-500cy) hides under 32 MFMAs + repack instead of sitting on the
//    per-phase critical path.
// Phase p=2a+pp covers kt in {4a+2pp, 4a+2pp+1}; both share a=p>>1 (same
// av2); kk=kt&3. buf=p&1 double-buffer: wave at phase p+2 repack cannot
// pass bar(p+1) until all waves finished their phase-p zs reads (R5-proven).
// ---------------------------------------------------------------------------
__global__ __launch_bounds__(256) void k_skip_mfma(
    const float* __restrict__ nf, const float* __restrict__ attrs,
    const unsigned short* __restrict__ B0, const unsigned short* __restrict__ B1,
    float* __restrict__ out_sc) {
  __shared__ __align__(16) unsigned short xs[64][136];       // 17408 B
  __shared__ float at[64][10];                               // 2560 B
  __shared__ __align__(16) unsigned short zs[2][2][64][40];  // 20480 B

  const int t = threadIdx.x;
  const int wave = t >> 6, lane = t & 63;
  const bool isG0 = blockIdx.x < 157;
  const int r0 = isG0 ? blockIdx.x * 64 : (blockIdx.x - 157) * 64;
  const int rcount = isG0 ? 10000 : 30000;
  const unsigned short* __restrict__ Bsw = isG0 ? B0 : B1;

  for (int idx = t; idx < 64 * 128; idx += 256) {
    const int i = idx >> 7, u = idx & 127;
    const int r = r0 + i;
    float v = 0.f;
    if (r < rcount) {
      if (isG0) v = nf[(size_t)r * 512 + u];
      else {
        const int n = r / 3, kc = r - n * 3;
        v = nf[(size_t)n * 512 + 128 + u * 3 + kc];
      }
    }
    xs[i][u] = f2h(v);
  }
  for (int idx = t; idx < 640; idx += 256) {
    const int i = idx / 10, a = idx - (idx / 10) * 10;
    const int r = r0 + i;
    float v = 0.f;
    if (r < rcount) v = attrs[(size_t)(isG0 ? r : r / 3) * 10 + a];
    at[i][a] = v;
  }
  __syncthreads();

  const int m = lane & 15, q = lane >> 4;
  const int colB = wave * 32;
  const int rr = t >> 2;
  const int off = (t & 3) * 8;

  // attr row -> 10 half2-broadcast registers (compile-time indexed)
  unsigned int atr2[10];
#pragma unroll
  for (int a = 0; a < 10; ++a) {
    const unsigned int h = f2h(at[rr][a]);
    atr2[a] = h | (h << 16);
  }

  f32x4 acc[4][2];
#pragma unroll
  for (int rt = 0; rt < 4; ++rt)
#pragma unroll
    for (int ct = 0; ct < 2; ++ct) acc[rt][ct] = (f32x4){0.f, 0.f, 0.f, 0.f};

  // prologue: prefetch bfrag for phase 0 (kt = 0, 1)
  f16x8 bf[2][2];
#pragma unroll
  for (int sub = 0; sub < 2; ++sub)
#pragma unroll
    for (int ct = 0; ct < 2; ++ct)
      bf[sub][ct] = *(const f16x8*)&Bsw[(size_t)(sub * 128 + colB + ct * 16 + m) * 32 + q * 8];

#pragma unroll
  for (int a = 0; a < 10; ++a) {
    const unsigned int av2 = atr2[a];
#pragma unroll
    for (int pp = 0; pp < 2; ++pp) {
      const int p = a * 2 + pp;
      const int buf = p & 1;
      // repack kt0 = 4a+2pp (kk=2pp) and kt1 = kt0+1 (kk=2pp+1)
#pragma unroll
      for (int sub = 0; sub < 2; ++sub) {
        const int kk = 2 * pp + sub;
        const uint4 xv = *(const uint4*)&xs[rr][kk * 32 + off];
        uint4 z;
        z.x = pkmul_h2(xv.x, av2);
        z.y = pkmul_h2(xv.y, av2);
        z.z = pkmul_h2(xv.z, av2);
        z.w = pkmul_h2(xv.w, av2);
        *(uint4*)&zs[buf][sub][rr][off] = z;
      }
      __syncthreads();

      // prefetch NEXT phase's bfrag (kt = 2p+2, 2p+3); consumed next phase
      f16x8 bfn[2][2];
      if (p < 19) {
        const int ktn = (p + 1) * 2;
#pragma unroll
        for (int sub = 0; sub < 2; ++sub)
#pragma unroll
          for (int ct = 0; ct < 2; ++ct)
            bfn[sub][ct] = *(const f16x8*)&Bsw[(size_t)((ktn + sub) * 128 + colB + ct * 16 + m) * 32 + q * 8];
      }

      // MFMAs for both K-steps of this phase (consume prefetched bf)
#pragma unroll
      for (int sub = 0; sub < 2; ++sub) {
#pragma unroll
        for (int rt = 0; rt < 4; ++rt) {
          const f16x8 afrag = *(const f16x8*)&zs[buf][sub][rt * 16 + m][q * 8];
#pragma unroll
          for (int ct = 0; ct < 2; ++ct)
            acc[rt][ct] = __builtin_amdgcn_mfma_f32_16x16x32_f16(
                afrag, bf[sub][ct], acc[rt][ct], 0, 0, 0);
        }
      }
      // rotate prefetch registers (dissolves in SSA under full unroll)
      bf[0][0] = bfn[0][0]; bf[0][1] = bfn[0][1];
      bf[1][0] = bfn[1][0]; bf[1][1] = bfn[1][1];
      // no trailing barrier: next phase writes the other zs buffer
    }
  }

#pragma unroll
  for (int rt = 0; rt < 4; ++rt) {
#pragma unroll
    for (int reg = 0; reg < 4; ++reg) {
      const int rloc = rt * 16 + q * 4 + reg;
      const int r = r0 + rloc;
      if (r < rcount) {
#pragma unroll
        for (int ct = 0; ct < 2; ++ct) {
          const int v = colB + ct * 16 + m;
          const float val = acc[rt][ct][reg] * INV_SQRT_CA;
          if (isG0) {
            out_sc[(size_t)r * 512 + v] = val;
          } else {
            const int n = r / 3, kc = r - (r / 3) * 3;
            out_sc[(size_t)n * 512 + 128 + v * 3 + kc] = val;
          }
        }
      }
    }
  }
}

// ---------------------------------------------------------------------------
// Sort-by-receiver: scan -> scatter (histogram lives in k_prep_node)
// ---------------------------------------------------------------------------
__global__ __launch_bounds__(1024) void k_scan(const int* __restrict__ counts,
                                               int* __restrict__ offsets,
                                               int* __restrict__ cursor) {
  __shared__ int part[1024];
  const int t = threadIdx.x;
  int local[10];
  int s = 0;
#pragma unroll
  for (int i = 0; i < 10; ++i) {
    const int idx = t * 10 + i;
    const int c = (idx < N_NODES) ? counts[idx] : 0;
    local[i] = s;
    s += c;
  }
  part[t] = s;
  __syncthreads();
  for (int off = 1; off < 1024; off <<= 1) {
    const int add = (t >= off) ? part[t - off] : 0;
    __syncthreads();
    part[t] += add;
    __syncthreads();
  }
  const int pre = (t > 0) ? part[t - 1] : 0;
#pragma unroll
  for (int i = 0; i < 10; ++i) {
    const int idx = t * 10 + i;
    if (idx < N_NODES) {
      const int o = pre + local[i];
      offsets[idx] = o;
      cursor[idx] = o;
    }
  }
  if (t == 1023) offsets[N_NODES] = part[1023];
}

__global__ __launch_bounds__(256) void k_scatter(
    const int* __restrict__ eidx, const float* __restrict__ ea_g,
    const float* __restrict__ ef_g,
    int* __restrict__ cursor,
    int* __restrict__ snd_s, int* __restrict__ rcv_s,
    float* __restrict__ ea_s, float* __restrict__ ef_s) {
  const int e = blockIdx.x * 256 + threadIdx.x;
  if (e < N_EDGES) {
    const int r = eidx[N_EDGES + e];
    const int pos = atomicAdd(&cursor[r], 1);
    snd_s[pos] = eidx[e];
    rcv_s[pos] = r;
    ((float4*)ea_s)[pos] = ((const float4*)ea_g)[e];
    ((float4*)ef_s)[pos * 2]     = ((const float4*)ef_g)[e * 2];
    ((float4*)ef_s)[pos * 2 + 1] = ((const float4*)ef_g)[e * 2 + 1];
  }
}

// ---------------------------------------------------------------------------
// K3 (R5-proven): edge MLP + messages + segmented reduce.
// ---------------------------------------------------------------------------
__global__ __launch_bounds__(256, 4) void k_mlp_msg(
    const float* __restrict__ ef_s, const float* __restrict__ ea_s,
    const int* __restrict__ snd_s, const int* __restrict__ rcv_s,
    const int* __restrict__ offsets,
    const float* __restrict__ R0, const unsigned short* __restrict__ R1a,
    const unsigned short* __restrict__ R2a, const unsigned short* __restrict__ R3a,
    const float* __restrict__ Wd, const __half* __restrict__ Hh,
    float* __restrict__ M, float* __restrict__ density) {
  __shared__ __align__(16) unsigned short actA[128][72];  // 18 KB
  __shared__ __align__(16) unsigned char uni[18432];      // 18 KB union
  __shared__ __align__(16) float ys[128][4];              // 2 KB
  __shared__ __align__(16) int sn[144];                   // 576 B
  __shared__ __align__(16) int rc[128];                   // 512 B
  float (*efs)[9] = (float (*)[9]) & uni[0];
  unsigned short (*actB)[72] = (unsigned short (*)[72]) & uni[0];
  __half (*wls2)[536] = (__half (*)[536]) & uni[0];

  const int t = threadIdx.x;
  const int wave = t >> 6, lane = t & 63, m = lane & 15, q = lane >> 4;
  const int e0 = blockIdx.x * 128;

  {
    const float4 v = *(const float4*)&ef_s[(size_t)e0 * 8 + t * 4];
    const int e = t >> 1, c0 = (t & 1) * 4;
    efs[e][c0] = v.x; efs[e][c0 + 1] = v.y;
    efs[e][c0 + 2] = v.z; efs[e][c0 + 3] = v.w;
  }
  if (t < 128) {
    *(float4*)&ys[t][0] = ((const float4*)ea_s)[e0 + t];
    sn[t] = snd_s[e0 + t];
    rc[t] = rcv_s[e0 + t];
  } else if (t < 144) {
    sn[t] = 0;
  }
  __syncthreads();

  const int u = t & 127, half = t >> 7;
  const size_t ucol = (size_t)(u << 2);
  uint2 hA[4], hB[4];
#pragma unroll
  for (int j = 0; j < 4; ++j)
    hA[j] = *(const uint2*)&Hh[(size_t)sn[j] * 512 + ucol];
#pragma unroll
  for (int j = 0; j < 4; ++j)
    hB[j] = *(const uint2*)&Hh[(size_t)sn[4 + j] * 512 + ucol];

  if (t < 128) {
    float s = 0.f;
#pragma unroll
    for (int i = 0; i < 8; ++i) s = fmaf(efs[t][i], Wd[i], s);
    s *= INV_SQRT_R;
    atomic_add_f32(&density[rc[t]], tanhf(s * s));
  }

  // L1
  {
    const int e = t & 127, j0 = (t >> 7) * 32;
    float a[32] = {};
#pragma unroll
    for (int i = 0; i < 8; ++i) {
      const float v = efs[e][i];
#pragma unroll
      for (int jj = 0; jj < 32; ++jj)
        a[jj] = fmaf(v, R0[i * 64 + j0 + jj], a[jj]);
    }
#pragma unroll
    for (int g = 0; g < 8; ++g) {
      uint2 pk;
      pk.x = pk2h(silu_f(a[4 * g] * INV_SQRT_R), silu_f(a[4 * g + 1] * INV_SQRT_R));
      pk.y = pk2h(silu_f(a[4 * g + 2] * INV_SQRT_R), silu_f(a[4 * g + 3] * INV_SQRT_R));
      *(uint2*)&actA[e][j0 + g * 4] = pk;
    }
  }
  __syncthreads();

  // L2
  {
    const f16x8 af0 = *(const f16x8*)&R1a[(((wave * 16 + m) * 2 + 0) << 5) + q * 8];
    const f16x8 af1 = *(const f16x8*)&R1a[(((wave * 16 + m) * 2 + 1) << 5) + q * 8];
#pragma unroll
    for (int et = 0; et < 8; ++et) {
      const f16x8 bf0 = *(const f16x8*)&actA[et * 16 + m][q * 8];
      const f16x8 bf1 = *(const f16x8*)&actA[et * 16 + m][32 + q * 8];
      f32x4 c = {0.f, 0.f, 0.f, 0.f};
      c = __builtin_amdgcn_mfma_f32_16x16x32_f16(af0, bf0, c, 0, 0, 0);
      c = __builtin_amdgcn_mfma_f32_16x16x32_f16(af1, bf1, c, 0, 0, 0);
      uint2 pk;
      pk.x = pk2h(silu_f(c[0] * INV_SQRT_64), silu_f(c[1] * INV_SQRT_64));
      pk.y = pk2h(silu_f(c[2] * INV_SQRT_64), silu_f(c[3] * INV_SQRT_64));
      *(uint2*)&actB[et * 16 + m][wave * 16 + q * 4] = pk;
    }
  }
  __syncthreads();

  // L3
  {
    const f16x8 af0 = *(const f16x8*)&R2a[(((wave * 16 + m) * 2 + 0) << 5) + q * 8];
    const f16x8 af1 = *(const f16x8*)&R2a[(((wave * 16 + m) * 2 + 1) << 5) + q * 8];
#pragma unroll
    for (int et = 0; et < 8; ++et) {
      const f16x8 bf0 = *(const f16x8*)&actB[et * 16 + m][q * 8];
      const f16x8 bf1 = *(const f16x8*)&actB[et * 16 + m][32 + q * 8];
      f32x4 c = {0.f, 0.f, 0.f, 0.f};
      c = __builtin_amdgcn_mfma_f32_16x16x32_f16(af0, bf0, c, 0, 0, 0);
      c = __builtin_amdgcn_mfma_f32_16x16x32_f16(af1, bf1, c, 0, 0, 0);
      uint2 pk;
      pk.x = pk2h(silu_f(c[0] * INV_SQRT_64), silu_f(c[1] * INV_SQRT_64));
      pk.y = pk2h(silu_f(c[2] * INV_SQRT_64), silu_f(c[3] * INV_SQRT_64));
      *(uint2*)&actA[et * 16 + m][wave * 16 + q * 4] = pk;
    }
  }
  __syncthreads();

  const int baseJ = (wave & 1) * 4 + (wave >> 1) * 16;
  f16x8 afL[4][2], afH[4][2];
#pragma unroll
  for (int i = 0; i < 4; ++i) {
#pragma unroll
    for (int kt = 0; kt < 2; ++kt) {
      const int JL = baseJ + i, JH = JL + 8;
      afL[i][kt] = *(const f16x8*)&R3a[(((JL * 16 + m) * 2 + kt) << 5) + q * 8];
      afH[i][kt] = *(const f16x8*)&R3a[(((JH * 16 + m) * 2 + kt) << 5) + q * 8];
    }
  }

  float a0 = 0.f, a1 = 0.f, a2 = 0.f, a3 = 0.f;
  int cur = rc[0];
  int s0c = offsets[cur], s1c = offsets[cur + 1];
  const int colx = (half ? 128 + u : u) * 2;

  auto flush = [&](int n, int s0, int s1) {
    float* Mp = &M[(size_t)n * 1024 + (half << 9) + (u << 2)];
    if (s0 >= e0 && s1 <= e0 + 128) {
      *(float4*)Mp = make_float4(a0, a1, a2, a3);
    } else {
      atomic_add_f32(Mp + 0, a0);
      atomic_add_f32(Mp + 1, a1);
      atomic_add_f32(Mp + 2, a2);
      atomic_add_f32(Mp + 3, a3);
    }
  };

  auto proc = [&](const uint2 hcur, unsigned int pr, const float4 yv, int n) {
    if (n != cur) {  // wave-uniform
      flush(cur, s0c, s1c);
      a0 = a1 = a2 = a3 = 0.f;
      cur = n;
      s0c = offsets[n];
      s1c = offsets[n + 1];
    }
    const float4 h4 = h4tof4(hcur);
    const __half2 ph = __builtin_bit_cast(__half2, pr);
    const float2 pw = __half22float2(ph);
    if (half == 0) {
      a0 = fmaf(pw.x * h4.x, yv.x, a0);
      const float c1 = pw.y * h4.x;
      a1 = fmaf(c1, yv.y, a1);
      a2 = fmaf(c1, yv.z, a2);
      a3 = fmaf(c1, yv.w, a3);
    } else {
      const float dt = h4.y * yv.y + h4.z * yv.z + h4.w * yv.w;
      a0 = fmaf(pw.y * dt, INV_SQRT_3, a0);
      const float c3 = pw.x * yv.x;
      a1 = fmaf(c3, h4.y, a1);
      a2 = fmaf(c3, h4.z, a2);
      a3 = fmaf(c3, h4.w, a3);
    }
  };

#define MSG_GROUP(G, HX)                                                    \
  {                                                                         \
    const int gb = ch * 16 + (G) * 4;                                       \
    unsigned int prv[4];                                                    \
    float4 yv4[4];                                                          \
    _Pragma("unroll") for (int j = 0; j < 4; ++j)                           \
        prv[j] = *(const unsigned int*)&wls2[(G) * 4 + j][colx];            \
    _Pragma("unroll") for (int j = 0; j < 4; ++j)                           \
        yv4[j] = *(const float4*)&ys[gb + j][0];                            \
    const int4 rc4 = *(const int4*)&rc[gb];                                 \
    proc(HX[0], prv[0], yv4[0], rc4.x);                                     \
    proc(HX[1], prv[1], yv4[1], rc4.y);                                     \
    proc(HX[2], prv[2], yv4[2], rc4.z);                                     \
    proc(HX[3], prv[3], yv4[3], rc4.w);                                     \
    const int4 sn4 = *(const int4*)&sn[gb + 8];                             \
    HX[0] = *(const uint2*)&Hh[(size_t)sn4.x * 512 + ucol];                 \
    HX[1] = *(const uint2*)&Hh[(size_t)sn4.y * 512 + ucol];                 \
    HX[2] = *(const uint2*)&Hh[(size_t)sn4.z * 512 + ucol];                 \
    HX[3] = *(const uint2*)&Hh[(size_t)sn4.w * 512 + ucol];                 \
  }

  // BARRIER-FREE chunk loop (wave w produces AND consumes wls2 [w*64,(w+1)*64))
#pragma unroll 1
  for (int ch = 0; ch < 8; ++ch) {
    {
      const f16x8 bf0 = *(const f16x8*)&actA[ch * 16 + m][q * 8];
      const f16x8 bf1 = *(const f16x8*)&actA[ch * 16 + m][32 + q * 8];
#pragma unroll
      for (int i = 0; i < 4; ++i) {
        f32x4 cL = {0.f, 0.f, 0.f, 0.f}, cH = {0.f, 0.f, 0.f, 0.f};
        cL = __builtin_amdgcn_mfma_f32_16x16x32_f16(afL[i][0], bf0, cL, 0, 0, 0);
        cL = __builtin_amdgcn_mfma_f32_16x16x32_f16(afL[i][1], bf1, cL, 0, 0, 0);
        cH = __builtin_amdgcn_mfma_f32_16x16x32_f16(afH[i][0], bf0, cH, 0, 0, 0);
        cH = __builtin_amdgcn_mfma_f32_16x16x32_f16(afH[i][1], bf1, cH, 0, 0, 0);
        uint4 pk;
        pk.x = pk2h(cL[0] * INV_SQRT_64, cH[0] * INV_SQRT_64);
        pk.y = pk2h(cL[1] * INV_SQRT_64, cH[1] * INV_SQRT_64);
        pk.z = pk2h(cL[2] * INV_SQRT_64, cH[2] * INV_SQRT_64);
        pk.w = pk2h(cL[3] * INV_SQRT_64, cH[3] * INV_SQRT_64);
        const int JL = baseJ + i;
        const int pidx0 = ((JL < 8) ? JL * 16 : (JL - 16) * 16 + 128) + q * 4;
        *(uint4*)&wls2[m][pidx0 * 2] = pk;
      }
    }
    MSG_GROUP(0, hA)
    MSG_GROUP(1, hB)
    MSG_GROUP(2, hA)
    MSG_GROUP(3, hB)
  }
#undef MSG_GROUP
  flush(cur, s0c, s1c);
}

// ---------------------------------------------------------------------------
// K5: out0 = M0 @ Wl0 /16/denom; out1[.,.,k] = M1[...,k] @ Wl1 /16/denom
// ---------------------------------------------------------------------------
__global__ __launch_bounds__(256) void k_out(
    const float* __restrict__ M, const float* __restrict__ density,
    const float* __restrict__ Wl0, const float* __restrict__ Wl1,
    float* __restrict__ out) {
  __shared__ __align__(16) float Ms[8][256][4];  // 32 KB
  __shared__ float dens[8];
  const int t = threadIdx.x;
  const int n0 = blockIdx.x * 8;
  const float4* Msrc = (const float4*)&M[(size_t)n0 * 1024];
  float4* Mdst = (float4*)&Ms[0][0][0];
  for (int idx = t; idx < 8 * 256; idx += 256) Mdst[idx] = Msrc[idx];
  if (t < 8) dens[t] = density[n0 + t] + 1.0f;
  __syncthreads();
  const int g = t >> 7, v = t & 127;
  float acc[4][4] = {};
  for (int p0 = 0; p0 < 256; p0 += 4) {
    float4 mv[4][4];
#pragma unroll
    for (int nn = 0; nn < 4; ++nn)
#pragma unroll
      for (int j = 0; j < 4; ++j)
        mv[nn][j] = *(const float4*)&Ms[g * 4 + nn][p0 + j][0];
#pragma unroll
    for (int j = 0; j < 4; ++j) {
      const float w0 = Wl0[(p0 + j) * C + v];
      const float w1 = Wl1[(p0 + j) * C + v];
#pragma unroll
      for (int nn = 0; nn < 4; ++nn) {
        acc[nn][0] = fmaf(mv[nn][j].x, w0, acc[nn][0]);
        acc[nn][1] = fmaf(mv[nn][j].y, w1, acc[nn][1]);
        acc[nn][2] = fmaf(mv[nn][j].z, w1, acc[nn][2]);
        acc[nn][3] = fmaf(mv[nn][j].w, w1, acc[nn][3]);
      }
    }
  }
#pragma unroll
  for (int nn = 0; nn < 4; ++nn) {
    const int n = n0 + g * 4 + nn;
    const float sc = INV_SQRT_2C / dens[g * 4 + nn];
    float4 o;
    o.x = acc[nn][0] * sc; o.y = acc[nn][1] * sc;
    o.z = acc[nn][2] * sc; o.w = acc[nn][3] * sc;
    *(float4*)&out[(size_t)n * 512 + v * 4] = o;
  }
}

// ---------------------------------------------------------------------------
extern "C" void kernel_launch(void* const* d_in, const int* in_sizes, int n_in,
                              void* d_out, int out_size, void* d_ws, size_t ws_size,
                              hipStream_t stream) {
  const float* node_attrs = (const float*)d_in[0];
  const float* node_feats = (const float*)d_in[1];
  const float* edge_attrs = (const float*)d_in[2];
  const float* edge_feats = (const float*)d_in[3];
  const int*   edge_index = (const int*)d_in[4];
  const float* W_up0 = (const float*)d_in[5];
  const float* W_up1 = (const float*)d_in[6];
  const float* R0 = (const float*)d_in[7];
  const float* R1 = (const float*)d_in[8];
  const float* R2 = (const float*)d_in[9];
  const float* R3 = (const float*)d_in[10];
  const float* Wd  = (const float*)d_in[11];
  const float* Wl0 = (const float*)d_in[12];
  const float* Wl1 = (const float*)d_in[13];
  const float* Ws0 = (const float*)d_in[14];
  const float* Ws1 = (const float*)d_in[15];
  float* out = (float*)d_out;

  __half* Hh = (__half*)d_ws;
  float* M = (float*)d_ws + (size_t)N_NODES * 512;
  float* density = M + (size_t)N_NODES * 1024;
  int* counts  = (int*)(density + 10000);
  int* offsets = counts + 10016;
  int* cursor  = offsets + 10016;
  int* snd_s   = cursor + 10016;
  int* rcv_s   = snd_s + N_EDGES;
  float* ea_s  = (float*)(rcv_s + N_EDGES);
  unsigned short* Bsw0 = (unsigned short*)(ea_s + (size_t)N_EDGES * 4);
  unsigned short* Bsw1 = Bsw0 + 1280 * 128;
  unsigned short* R1a  = Bsw1 + 1280 * 128;
  unsigned short* R2a  = R1a + 64 * 64;
  unsigned short* R3a  = R2a + 64 * 64;
  float* ef_s  = (float*)(R3a + 64 * 512);

  hipMemsetAsync(M, 0, ((size_t)N_NODES * 1024 + 10000 + 10016) * sizeof(float),
                 stream);

  k_prep_node<<<2550, 256, 0, stream>>>(node_feats, W_up0, W_up1, Hh, Ws0, Ws1,
                                        Bsw0, Bsw1, R1, R1a, R2, R2a, R3, R3a,
                                        edge_index, counts);
  k_scan<<<1, 1024, 0, stream>>>(counts, offsets, cursor);
  k_scatter<<<(N_EDGES + 255) / 256, 256, 0, stream>>>(
      edge_index, edge_attrs, edge_feats, cursor, snd_s, rcv_s, ea_s, ef_s);
  k_mlp_msg<<<N_EDGES / 128, 256, 0, stream>>>(ef_s, ea_s, snd_s, rcv_s,
                                               offsets, R0, R1a, R2a, R3a, Wd,
                                               Hh, M, density);
  k_out<<<N_NODES / 8, 256, 0, stream>>>(M, density, Wl0, Wl1, out);
  k_skip_mfma<<<157 + 469, 256, 0, stream>>>(node_feats, node_attrs, Bsw0, Bsw1,
                                             out + (size_t)N_NODES * 512);
}

// Round 9
// 278.179 us; speedup vs baseline: 1.4067x; 1.1463x over previous
//
#include <hip/hip_runtime.h>
#include <hip/hip_bf16.h>
#include <hip/hip_fp16.h>

// Problem constants
#define N_NODES 10000
#define N_EDGES 128000
constexpr int C = 128;
constexpr int A = 10;

constexpr float INV_SQRT_C  = 0.08838834764831845f;   // 1/sqrt(128)
constexpr float INV_SQRT_R  = 0.35355339059327373f;   // 1/sqrt(8)
constexpr float INV_SQRT_64 = 0.125f;                 // 1/sqrt(64)
constexpr float INV_SQRT_CA = 0.027950849718747374f;  // 1/sqrt(1280)
constexpr float INV_SQRT_2C = 0.0625f;                // 1/sqrt(256)
constexpr float INV_SQRT_3  = 0.57735026918962576f;

typedef short short8 __attribute__((ext_vector_type(8)));
typedef _Float16 f16x8 __attribute__((ext_vector_type(8)));
typedef _Float16 f16x2 __attribute__((ext_vector_type(2)));
typedef float f32x4 __attribute__((ext_vector_type(4)));

__device__ __forceinline__ float silu_f(float x) { return x / (1.0f + __expf(-x)); }

__device__ __forceinline__ void atomic_add_f32(float* p, float v) {
  __hip_atomic_fetch_add(p, v, __ATOMIC_RELAXED, __HIP_MEMORY_SCOPE_AGENT);
}

__device__ __forceinline__ unsigned short f2h(float f) {
  return __builtin_bit_cast(unsigned short, (_Float16)f);  // RNE
}

__device__ __forceinline__ unsigned int pk2h(float a, float b) {
  auto h = __builtin_amdgcn_cvt_pkrtz(a, b);  // __fp16 ext_vector(2)
  return __builtin_bit_cast(unsigned int, h);
}

__device__ __forceinline__ unsigned int pkmul_h2(unsigned int x, unsigned int y) {
  const f16x2 a = __builtin_bit_cast(f16x2, x), b = __builtin_bit_cast(f16x2, y);
  return __builtin_bit_cast(unsigned int, a * b);  // v_pk_mul_f16
}

__device__ __forceinline__ float4 h4tof4(uint2 v) {
  const __half2 lo = __builtin_bit_cast(__half2, v.x);
  const __half2 hi = __builtin_bit_cast(__half2, v.y);
  const float2 flo = __half22float2(lo), fhi = __half22float2(hi);
  return make_float4(flo.x, flo.y, fhi.x, fhi.y);
}

// ---------------------------------------------------------------------------
// cvtw helper: weight (K x N fp32, row-major) -> f16 A/B-operand swizzle.
// dst[((n*KT + (k>>5))<<5) + (k&31)]
// ---------------------------------------------------------------------------
__device__ __forceinline__ void cvtw(const float* __restrict__ src,
                                     unsigned short* __restrict__ dst,
                                     int idx, int lgN, int KT) {
  const int k = idx >> lgN;
  const int n = idx & ((1 << lgN) - 1);
  dst[((n * KT + (k >> 5)) << 5) + (k & 31)] = f2h(src[idx]);
}

// ---------------------------------------------------------------------------
// k_prep: skip-weight cvt (f16, k'=a*128+u) + R1/R2/R3 cvt + Wu0/Wu1 cvt
// (KT=4, for k_node_mfma) + Wl0/Wl1 cvt (KT=8, for k_out_mfma) + histogram.
// ---------------------------------------------------------------------------
__global__ __launch_bounds__(256) void k_prep(
    const float* __restrict__ W0, const float* __restrict__ W1,
    unsigned short* __restrict__ B0, unsigned short* __restrict__ B1,
    const float* __restrict__ R1, unsigned short* __restrict__ R1a,
    const float* __restrict__ R2, unsigned short* __restrict__ R2a,
    const float* __restrict__ R3, unsigned short* __restrict__ R3a,
    const float* __restrict__ Wu0, unsigned short* __restrict__ Wua0,
    const float* __restrict__ Wu1, unsigned short* __restrict__ Wua1,
    const float* __restrict__ Wl0, unsigned short* __restrict__ Wla0,
    const float* __restrict__ Wl1, unsigned short* __restrict__ Wla1,
    const int* __restrict__ eidx, int* __restrict__ counts) {
  const int b = blockIdx.x, t = threadIdx.x;
  if (b < 640) {
    // skip GEMM B operand: k = u*10+a -> permuted k' = a*128+u
    const int idx = b * 256 + t;
    const int k = idx >> 7, col = idx & 127;
    const int u = k / 10, a = k - u * 10;
    const int kp = a * 128 + u;
    const int dst = ((kp >> 5) * 128 + col) * 32 + (kp & 31);
    B0[dst] = f2h(W0[idx]);
    B1[dst] = f2h(W1[idx]);
  } else if (b < 656) {
    cvtw(R1, R1a, (b - 640) * 256 + t, 6, 2);
  } else if (b < 672) {
    cvtw(R2, R2a, (b - 656) * 256 + t, 6, 2);
  } else if (b < 800) {
    cvtw(R3, R3a, (b - 672) * 256 + t, 9, 2);
  } else if (b < 864) {
    cvtw(Wu0, Wua0, (b - 800) * 256 + t, 7, 4);
  } else if (b < 928) {
    cvtw(Wu1, Wua1, (b - 864) * 256 + t, 7, 4);
  } else if (b < 1056) {
    cvtw(Wl0, Wla0, (b - 928) * 256 + t, 7, 8);
  } else if (b < 1184) {
    cvtw(Wl1, Wla1, (b - 1056) * 256 + t, 7, 8);
  } else {
    const int e = (b - 1184) * 256 + t;
    if (e < N_EDGES) atomicAdd(&counts[eidx[N_EDGES + e]], 1);
  }
}

// ---------------------------------------------------------------------------
// k_node_mfma: H = node-up GEMM via f16 MFMA (was fp32 VALU, ~2048 serial
// FMA/thread). One block = 16 nodes, 64 A-rows: rows 0-15 = x0 (B=Wu0),
// rows 16-63 = x1(n,kc) (B=Wu1; per-rt B selection -> one block produces
// ALL 4 H components of its nodes). Epilogue stages to LDS then emits
// coalesced uint2 stores (R4 lesson: scattered 2B global stores regress).
// Fragment indexing copied verbatim from the test-verified k_skip_mfma.
// ---------------------------------------------------------------------------
__global__ __launch_bounds__(256) void k_node_mfma(
    const float* __restrict__ nf, const unsigned short* __restrict__ Wua0,
    const unsigned short* __restrict__ Wua1, __half* __restrict__ Hh) {
  __shared__ __align__(16) unsigned short xs[64][136];   // 17408 B
  __shared__ __align__(16) unsigned short hst[16][512];  // 16384 B
  const int t = threadIdx.x;
  const int wave = t >> 6, lane = t & 63, m = lane & 15, q = lane >> 4;
  const int n0 = blockIdx.x * 16;

  // stage: rows 0-15 <- x0; rows 16+3*nn+kc <- x1[nn,:,kc]
  for (int i = t; i < 2048; i += 256) {
    const int nn = i >> 7, qq = (i & 127) * 4;
    const float4 v = *(const float4*)&nf[(size_t)(n0 + nn) * 512 + qq];
    const float vals[4] = {v.x, v.y, v.z, v.w};
    if (qq < 128) {
#pragma unroll
      for (int j = 0; j < 4; ++j) xs[nn][qq + j] = f2h(vals[j]);
    } else {
#pragma unroll
      for (int j = 0; j < 4; ++j) {
        const int r = qq + j - 128;
        const int u = r / 3, kc = r - u * 3;
        xs[16 + nn * 3 + kc][u] = f2h(vals[j]);
      }
    }
  }
  __syncthreads();

  const int colB = wave * 32;
  f32x4 acc[4][2];
#pragma unroll
  for (int rt = 0; rt < 4; ++rt)
#pragma unroll
    for (int ct = 0; ct < 2; ++ct) acc[rt][ct] = (f32x4){0.f, 0.f, 0.f, 0.f};

#pragma unroll
  for (int kt = 0; kt < 4; ++kt) {
    f16x8 bf0[2], bf1[2];
#pragma unroll
    for (int ct = 0; ct < 2; ++ct) {
      const int col = colB + ct * 16 + m;
      bf0[ct] = *(const f16x8*)&Wua0[((col * 4 + kt) << 5) + q * 8];
      bf1[ct] = *(const f16x8*)&Wua1[((col * 4 + kt) << 5) + q * 8];
    }
#pragma unroll
    for (int rt = 0; rt < 4; ++rt) {
      const f16x8 af = *(const f16x8*)&xs[rt * 16 + m][kt * 32 + q * 8];
#pragma unroll
      for (int ct = 0; ct < 2; ++ct)
        acc[rt][ct] = __builtin_amdgcn_mfma_f32_16x16x32_f16(
            af, rt == 0 ? bf0[ct] : bf1[ct], acc[rt][ct], 0, 0, 0);
    }
  }

  // epilogue: D row=rt*16+q*4+reg, col=colB+ct*16+m -> hst[node][4v+comp]
#pragma unroll
  for (int rt = 0; rt < 4; ++rt) {
#pragma unroll
    for (int reg = 0; reg < 4; ++reg) {
      const int rloc = rt * 16 + q * 4 + reg;
#pragma unroll
      for (int ct = 0; ct < 2; ++ct) {
        const int v = colB + ct * 16 + m;
        const unsigned short hv = f2h(acc[rt][ct][reg] * INV_SQRT_C);
        if (rt == 0) {
          hst[rloc][v * 4] = hv;
        } else {
          const int rr = rloc - 16;
          const int nn = rr / 3, kc = rr - nn * 3;
          hst[nn][v * 4 + 1 + kc] = hv;
        }
      }
    }
  }
  __syncthreads();
  // coalesced uint2 stores
  for (int i = t; i < 2048; i += 256) {
    const int nn = i >> 7, pos = i & 127;
    *(uint2*)&Hh[(size_t)(n0 + nn) * 512 + pos * 4] =
        *(const uint2*)&hst[nn][pos * 4];
  }
}

// ---------------------------------------------------------------------------
// K2 v4 (R8-proven): sc GEMM, 2 K-steps/phase (20 barriers) + cross-phase
// bfrag prefetch.
// ---------------------------------------------------------------------------
__global__ __launch_bounds__(256) void k_skip_mfma(
    const float* __restrict__ nf, const float* __restrict__ attrs,
    const unsigned short* __restrict__ B0, const unsigned short* __restrict__ B1,
    float* __restrict__ out_sc) {
  __shared__ __align__(16) unsigned short xs[64][136];       // 17408 B
  __shared__ float at[64][10];                               // 2560 B
  __shared__ __align__(16) unsigned short zs[2][2][64][40];  // 20480 B

  const int t = threadIdx.x;
  const int wave = t >> 6, lane = t & 63;
  const bool isG0 = blockIdx.x < 157;
  const int r0 = isG0 ? blockIdx.x * 64 : (blockIdx.x - 157) * 64;
  const int rcount = isG0 ? 10000 : 30000;
  const unsigned short* __restrict__ Bsw = isG0 ? B0 : B1;

  for (int idx = t; idx < 64 * 128; idx += 256) {
    const int i = idx >> 7, u = idx & 127;
    const int r = r0 + i;
    float v = 0.f;
    if (r < rcount) {
      if (isG0) v = nf[(size_t)r * 512 + u];
      else {
        const int n = r / 3, kc = r - n * 3;
        v = nf[(size_t)n * 512 + 128 + u * 3 + kc];
      }
    }
    xs[i][u] = f2h(v);
  }
  for (int idx = t; idx < 640; idx += 256) {
    const int i = idx / 10, a = idx - (idx / 10) * 10;
    const int r = r0 + i;
    float v = 0.f;
    if (r < rcount) v = attrs[(size_t)(isG0 ? r : r / 3) * 10 + a];
    at[i][a] = v;
  }
  __syncthreads();

  const int m = lane & 15, q = lane >> 4;
  const int colB = wave * 32;
  const int rr = t >> 2;
  const int off = (t & 3) * 8;

  unsigned int atr2[10];
#pragma unroll
  for (int a = 0; a < 10; ++a) {
    const unsigned int h = f2h(at[rr][a]);
    atr2[a] = h | (h << 16);
  }

  f32x4 acc[4][2];
#pragma unroll
  for (int rt = 0; rt < 4; ++rt)
#pragma unroll
    for (int ct = 0; ct < 2; ++ct) acc[rt][ct] = (f32x4){0.f, 0.f, 0.f, 0.f};

  // prologue: prefetch bfrag for phase 0 (kt = 0, 1)
  f16x8 bf[2][2];
#pragma unroll
  for (int sub = 0; sub < 2; ++sub)
#pragma unroll
    for (int ct = 0; ct < 2; ++ct)
      bf[sub][ct] = *(const f16x8*)&Bsw[(size_t)(sub * 128 + colB + ct * 16 + m) * 32 + q * 8];

#pragma unroll
  for (int a = 0; a < 10; ++a) {
    const unsigned int av2 = atr2[a];
#pragma unroll
    for (int pp = 0; pp < 2; ++pp) {
      const int p = a * 2 + pp;
      const int buf = p & 1;
#pragma unroll
      for (int sub = 0; sub < 2; ++sub) {
        const int kk = 2 * pp + sub;
        const uint4 xv = *(const uint4*)&xs[rr][kk * 32 + off];
        uint4 z;
        z.x = pkmul_h2(xv.x, av2);
        z.y = pkmul_h2(xv.y, av2);
        z.z = pkmul_h2(xv.z, av2);
        z.w = pkmul_h2(xv.w, av2);
        *(uint4*)&zs[buf][sub][rr][off] = z;
      }
      __syncthreads();

      f16x8 bfn[2][2];
      if (p < 19) {
        const int ktn = (p + 1) * 2;
#pragma unroll
        for (int sub = 0; sub < 2; ++sub)
#pragma unroll
          for (int ct = 0; ct < 2; ++ct)
            bfn[sub][ct] = *(const f16x8*)&Bsw[(size_t)((ktn + sub) * 128 + colB + ct * 16 + m) * 32 + q * 8];
      }

#pragma unroll
      for (int sub = 0; sub < 2; ++sub) {
#pragma unroll
        for (int rt = 0; rt < 4; ++rt) {
          const f16x8 afrag = *(const f16x8*)&zs[buf][sub][rt * 16 + m][q * 8];
#pragma unroll
          for (int ct = 0; ct < 2; ++ct)
            acc[rt][ct] = __builtin_amdgcn_mfma_f32_16x16x32_f16(
                afrag, bf[sub][ct], acc[rt][ct], 0, 0, 0);
        }
      }
      bf[0][0] = bfn[0][0]; bf[0][1] = bfn[0][1];
      bf[1][0] = bfn[1][0]; bf[1][1] = bfn[1][1];
    }
  }

#pragma unroll
  for (int rt = 0; rt < 4; ++rt) {
#pragma unroll
    for (int reg = 0; reg < 4; ++reg) {
      const int rloc = rt * 16 + q * 4 + reg;
      const int r = r0 + rloc;
      if (r < rcount) {
#pragma unroll
        for (int ct = 0; ct < 2; ++ct) {
          const int v = colB + ct * 16 + m;
          const float val = acc[rt][ct][reg] * INV_SQRT_CA;
          if (isG0) {
            out_sc[(size_t)r * 512 + v] = val;
          } else {
            const int n = r / 3, kc = r - (r / 3) * 3;
            out_sc[(size_t)n * 512 + 128 + v * 3 + kc] = val;
          }
        }
      }
    }
  }
}

// ---------------------------------------------------------------------------
// Sort-by-receiver: scan -> scatter (histogram lives in k_prep)
// ---------------------------------------------------------------------------
__global__ __launch_bounds__(1024) void k_scan(const int* __restrict__ counts,
                                               int* __restrict__ offsets,
                                               int* __restrict__ cursor) {
  __shared__ int part[1024];
  const int t = threadIdx.x;
  int local[10];
  int s = 0;
#pragma unroll
  for (int i = 0; i < 10; ++i) {
    const int idx = t * 10 + i;
    const int c = (idx < N_NODES) ? counts[idx] : 0;
    local[i] = s;
    s += c;
  }
  part[t] = s;
  __syncthreads();
  for (int off = 1; off < 1024; off <<= 1) {
    const int add = (t >= off) ? part[t - off] : 0;
    __syncthreads();
    part[t] += add;
    __syncthreads();
  }
  const int pre = (t > 0) ? part[t - 1] : 0;
#pragma unroll
  for (int i = 0; i < 10; ++i) {
    const int idx = t * 10 + i;
    if (idx < N_NODES) {
      const int o = pre + local[i];
      offsets[idx] = o;
      cursor[idx] = o;
    }
  }
  if (t == 1023) offsets[N_NODES] = part[1023];
}

__global__ __launch_bounds__(256) void k_scatter(
    const int* __restrict__ eidx, const float* __restrict__ ea_g,
    const float* __restrict__ ef_g,
    int* __restrict__ cursor,
    int* __restrict__ snd_s, int* __restrict__ rcv_s,
    float* __restrict__ ea_s, float* __restrict__ ef_s) {
  const int e = blockIdx.x * 256 + threadIdx.x;
  if (e < N_EDGES) {
    const int r = eidx[N_EDGES + e];
    const int pos = atomicAdd(&cursor[r], 1);
    snd_s[pos] = eidx[e];
    rcv_s[pos] = r;
    ((float4*)ea_s)[pos] = ((const float4*)ea_g)[e];
    ((float4*)ef_s)[pos * 2]     = ((const float4*)ef_g)[e * 2];
    ((float4*)ef_s)[pos * 2 + 1] = ((const float4*)ef_g)[e * 2 + 1];
  }
}

// ---------------------------------------------------------------------------
// K3 (R5-proven): edge MLP + messages + segmented reduce.
// ---------------------------------------------------------------------------
__global__ __launch_bounds__(256, 4) void k_mlp_msg(
    const float* __restrict__ ef_s, const float* __restrict__ ea_s,
    const int* __restrict__ snd_s, const int* __restrict__ rcv_s,
    const int* __restrict__ offsets,
    const float* __restrict__ R0, const unsigned short* __restrict__ R1a,
    const unsigned short* __restrict__ R2a, const unsigned short* __restrict__ R3a,
    const float* __restrict__ Wd, const __half* __restrict__ Hh,
    float* __restrict__ M, float* __restrict__ density) {
  __shared__ __align__(16) unsigned short actA[128][72];  // 18 KB
  __shared__ __align__(16) unsigned char uni[18432];      // 18 KB union
  __shared__ __align__(16) float ys[128][4];              // 2 KB
  __shared__ __align__(16) int sn[144];                   // 576 B
  __shared__ __align__(16) int rc[128];                   // 512 B
  float (*efs)[9] = (float (*)[9]) & uni[0];
  unsigned short (*actB)[72] = (unsigned short (*)[72]) & uni[0];
  __half (*wls2)[536] = (__half (*)[536]) & uni[0];

  const int t = threadIdx.x;
  const int wave = t >> 6, lane = t & 63, m = lane & 15, q = lane >> 4;
  const int e0 = blockIdx.x * 128;

  {
    const float4 v = *(const float4*)&ef_s[(size_t)e0 * 8 + t * 4];
    const int e = t >> 1, c0 = (t & 1) * 4;
    efs[e][c0] = v.x; efs[e][c0 + 1] = v.y;
    efs[e][c0 + 2] = v.z; efs[e][c0 + 3] = v.w;
  }
  if (t < 128) {
    *(float4*)&ys[t][0] = ((const float4*)ea_s)[e0 + t];
    sn[t] = snd_s[e0 + t];
    rc[t] = rcv_s[e0 + t];
  } else if (t < 144) {
    sn[t] = 0;
  }
  __syncthreads();

  const int u = t & 127, half = t >> 7;
  const size_t ucol = (size_t)(u << 2);
  uint2 hA[4], hB[4];
#pragma unroll
  for (int j = 0; j < 4; ++j)
    hA[j] = *(const uint2*)&Hh[(size_t)sn[j] * 512 + ucol];
#pragma unroll
  for (int j = 0; j < 4; ++j)
    hB[j] = *(const uint2*)&Hh[(size_t)sn[4 + j] * 512 + ucol];

  if (t < 128) {
    float s = 0.f;
#pragma unroll
    for (int i = 0; i < 8; ++i) s = fmaf(efs[t][i], Wd[i], s);
    s *= INV_SQRT_R;
    atomic_add_f32(&density[rc[t]], tanhf(s * s));
  }

  // L1
  {
    const int e = t & 127, j0 = (t >> 7) * 32;
    float a[32] = {};
#pragma unroll
    for (int i = 0; i < 8; ++i) {
      const float v = efs[e][i];
#pragma unroll
      for (int jj = 0; jj < 32; ++jj)
        a[jj] = fmaf(v, R0[i * 64 + j0 + jj], a[jj]);
    }
#pragma unroll
    for (int g = 0; g < 8; ++g) {
      uint2 pk;
      pk.x = pk2h(silu_f(a[4 * g] * INV_SQRT_R), silu_f(a[4 * g + 1] * INV_SQRT_R));
      pk.y = pk2h(silu_f(a[4 * g + 2] * INV_SQRT_R), silu_f(a[4 * g + 3] * INV_SQRT_R));
      *(uint2*)&actA[e][j0 + g * 4] = pk;
    }
  }
  __syncthreads();

  // L2
  {
    const f16x8 af0 = *(const f16x8*)&R1a[(((wave * 16 + m) * 2 + 0) << 5) + q * 8];
    const f16x8 af1 = *(const f16x8*)&R1a[(((wave * 16 + m) * 2 + 1) << 5) + q * 8];
#pragma unroll
    for (int et = 0; et < 8; ++et) {
      const f16x8 bf0 = *(const f16x8*)&actA[et * 16 + m][q * 8];
      const f16x8 bf1 = *(const f16x8*)&actA[et * 16 + m][32 + q * 8];
      f32x4 c = {0.f, 0.f, 0.f, 0.f};
      c = __builtin_amdgcn_mfma_f32_16x16x32_f16(af0, bf0, c, 0, 0, 0);
      c = __builtin_amdgcn_mfma_f32_16x16x32_f16(af1, bf1, c, 0, 0, 0);
      uint2 pk;
      pk.x = pk2h(silu_f(c[0] * INV_SQRT_64), silu_f(c[1] * INV_SQRT_64));
      pk.y = pk2h(silu_f(c[2] * INV_SQRT_64), silu_f(c[3] * INV_SQRT_64));
      *(uint2*)&actB[et * 16 + m][wave * 16 + q * 4] = pk;
    }
  }
  __syncthreads();

  // L3
  {
    const f16x8 af0 = *(const f16x8*)&R2a[(((wave * 16 + m) * 2 + 0) << 5) + q * 8];
    const f16x8 af1 = *(const f16x8*)&R2a[(((wave * 16 + m) * 2 + 1) << 5) + q * 8];
#pragma unroll
    for (int et = 0; et < 8; ++et) {
      const f16x8 bf0 = *(const f16x8*)&actB[et * 16 + m][q * 8];
      const f16x8 bf1 = *(const f16x8*)&actB[et * 16 + m][32 + q * 8];
      f32x4 c = {0.f, 0.f, 0.f, 0.f};
      c = __builtin_amdgcn_mfma_f32_16x16x32_f16(af0, bf0, c, 0, 0, 0);
      c = __builtin_amdgcn_mfma_f32_16x16x32_f16(af1, bf1, c, 0, 0, 0);
      uint2 pk;
      pk.x = pk2h(silu_f(c[0] * INV_SQRT_64), silu_f(c[1] * INV_SQRT_64));
      pk.y = pk2h(silu_f(c[2] * INV_SQRT_64), silu_f(c[3] * INV_SQRT_64));
      *(uint2*)&actA[et * 16 + m][wave * 16 + q * 4] = pk;
    }
  }
  __syncthreads();

  const int baseJ = (wave & 1) * 4 + (wave >> 1) * 16;
  f16x8 afL[4][2], afH[4][2];
#pragma unroll
  for (int i = 0; i < 4; ++i) {
#pragma unroll
    for (int kt = 0; kt < 2; ++kt) {
      const int JL = baseJ + i, JH = JL + 8;
      afL[i][kt] = *(const f16x8*)&R3a[(((JL * 16 + m) * 2 + kt) << 5) + q * 8];
      afH[i][kt] = *(const f16x8*)&R3a[(((JH * 16 + m) * 2 + kt) << 5) + q * 8];
    }
  }

  float a0 = 0.f, a1 = 0.f, a2 = 0.f, a3 = 0.f;
  int cur = rc[0];
  int s0c = offsets[cur], s1c = offsets[cur + 1];
  const int colx = (half ? 128 + u : u) * 2;

  auto flush = [&](int n, int s0, int s1) {
    float* Mp = &M[(size_t)n * 1024 + (half << 9) + (u << 2)];
    if (s0 >= e0 && s1 <= e0 + 128) {
      *(float4*)Mp = make_float4(a0, a1, a2, a3);
    } else {
      atomic_add_f32(Mp + 0, a0);
      atomic_add_f32(Mp + 1, a1);
      atomic_add_f32(Mp + 2, a2);
      atomic_add_f32(Mp + 3, a3);
    }
  };

  auto proc = [&](const uint2 hcur, unsigned int pr, const float4 yv, int n) {
    if (n != cur) {  // wave-uniform
      flush(cur, s0c, s1c);
      a0 = a1 = a2 = a3 = 0.f;
      cur = n;
      s0c = offsets[n];
      s1c = offsets[n + 1];
    }
    const float4 h4 = h4tof4(hcur);
    const __half2 ph = __builtin_bit_cast(__half2, pr);
    const float2 pw = __half22float2(ph);
    if (half == 0) {
      a0 = fmaf(pw.x * h4.x, yv.x, a0);
      const float c1 = pw.y * h4.x;
      a1 = fmaf(c1, yv.y, a1);
      a2 = fmaf(c1, yv.z, a2);
      a3 = fmaf(c1, yv.w, a3);
    } else {
      const float dt = h4.y * yv.y + h4.z * yv.z + h4.w * yv.w;
      a0 = fmaf(pw.y * dt, INV_SQRT_3, a0);
      const float c3 = pw.x * yv.x;
      a1 = fmaf(c3, h4.y, a1);
      a2 = fmaf(c3, h4.z, a2);
      a3 = fmaf(c3, h4.w, a3);
    }
  };

#define MSG_GROUP(G, HX)                                                    \
  {                                                                         \
    const int gb = ch * 16 + (G) * 4;                                       \
    unsigned int prv[4];                                                    \
    float4 yv4[4];                                                          \
    _Pragma("unroll") for (int j = 0; j < 4; ++j)                           \
        prv[j] = *(const unsigned int*)&wls2[(G) * 4 + j][colx];            \
    _Pragma("unroll") for (int j = 0; j < 4; ++j)                           \
        yv4[j] = *(const float4*)&ys[gb + j][0];                            \
    const int4 rc4 = *(const int4*)&rc[gb];                                 \
    proc(HX[0], prv[0], yv4[0], rc4.x);                                     \
    proc(HX[1], prv[1], yv4[1], rc4.y);                                     \
    proc(HX[2], prv[2], yv4[2], rc4.z);                                     \
    proc(HX[3], prv[3], yv4[3], rc4.w);                                     \
    const int4 sn4 = *(const int4*)&sn[gb + 8];                             \
    HX[0] = *(const uint2*)&Hh[(size_t)sn4.x * 512 + ucol];                 \
    HX[1] = *(const uint2*)&Hh[(size_t)sn4.y * 512 + ucol];                 \
    HX[2] = *(const uint2*)&Hh[(size_t)sn4.z * 512 + ucol];                 \
    HX[3] = *(const uint2*)&Hh[(size_t)sn4.w * 512 + ucol];                 \
  }

  // BARRIER-FREE chunk loop (wave w produces AND consumes wls2 [w*64,(w+1)*64))
#pragma unroll 1
  for (int ch = 0; ch < 8; ++ch) {
    {
      const f16x8 bf0 = *(const f16x8*)&actA[ch * 16 + m][q * 8];
      const f16x8 bf1 = *(const f16x8*)&actA[ch * 16 + m][32 + q * 8];
#pragma unroll
      for (int i = 0; i < 4; ++i) {
        f32x4 cL = {0.f, 0.f, 0.f, 0.f}, cH = {0.f, 0.f, 0.f, 0.f};
        cL = __builtin_amdgcn_mfma_f32_16x16x32_f16(afL[i][0], bf0, cL, 0, 0, 0);
        cL = __builtin_amdgcn_mfma_f32_16x16x32_f16(afL[i][1], bf1, cL, 0, 0, 0);
        cH = __builtin_amdgcn_mfma_f32_16x16x32_f16(afH[i][0], bf0, cH, 0, 0, 0);
        cH = __builtin_amdgcn_mfma_f32_16x16x32_f16(afH[i][1], bf1, cH, 0, 0, 0);
        uint4 pk;
        pk.x = pk2h(cL[0] * INV_SQRT_64, cH[0] * INV_SQRT_64);
        pk.y = pk2h(cL[1] * INV_SQRT_64, cH[1] * INV_SQRT_64);
        pk.z = pk2h(cL[2] * INV_SQRT_64, cH[2] * INV_SQRT_64);
        pk.w = pk2h(cL[3] * INV_SQRT_64, cH[3] * INV_SQRT_64);
        const int JL = baseJ + i;
        const int pidx0 = ((JL < 8) ? JL * 16 : (JL - 16) * 16 + 128) + q * 4;
        *(uint4*)&wls2[m][pidx0 * 2] = pk;
      }
    }
    MSG_GROUP(0, hA)
    MSG_GROUP(1, hB)
    MSG_GROUP(2, hA)
    MSG_GROUP(3, hB)
  }
#undef MSG_GROUP
  flush(cur, s0c, s1c);
}

// ---------------------------------------------------------------------------
// k_out_mfma: out = M@Wl via f16 MFMA (was fp32 VALU ~4096 FMA/thread).
// One block = 16 nodes, 64 A-rows (rows 0-15 = M0 / Wl0; rows 16-63 =
// M1(n,kc) / Wl1), K=256. A staged as f16 in LDS; epilogue stages to ost
// (aliases xso, barrier-separated) -> coalesced float4 out-writes.
// ---------------------------------------------------------------------------
__global__ __launch_bounds__(256) void k_out_mfma(
    const float* __restrict__ M, const float* __restrict__ density,
    const unsigned short* __restrict__ Wla0,
    const unsigned short* __restrict__ Wla1, float* __restrict__ out) {
  __shared__ __align__(16) unsigned char sm[64 * 264 * 2];  // 33792 B union
  __shared__ float dens[16];
  unsigned short (*xso)[264] = (unsigned short (*)[264])sm;  // [64][264] f16
  float (*ost)[512] = (float (*)[512])sm;                    // 32768 B
  const int t = threadIdx.x;
  const int wave = t >> 6, lane = t & 63, m = lane & 15, q = lane >> 4;
  const int n0 = blockIdx.x * 16;

  if (t < 16) dens[t] = INV_SQRT_2C / (density[n0 + t] + 1.0f);

  // stage M -> f16 rows: float4 = (c0,c1,c2,c3) of (nn, p=h*128+u)
  const float4* Mf4 = (const float4*)&M[(size_t)n0 * 1024];
  for (int i = t; i < 4096; i += 256) {
    const float4 v = Mf4[i];
    const int nn = i >> 8, p = i & 255;
    xso[nn][p] = f2h(v.x);
    const int rb = 16 + nn * 3;
    xso[rb][p] = f2h(v.y);
    xso[rb + 1][p] = f2h(v.z);
    xso[rb + 2][p] = f2h(v.w);
  }
  __syncthreads();

  const int colB = wave * 32;
  f32x4 acc[4][2];
#pragma unroll
  for (int rt = 0; rt < 4; ++rt)
#pragma unroll
    for (int ct = 0; ct < 2; ++ct) acc[rt][ct] = (f32x4){0.f, 0.f, 0.f, 0.f};

#pragma unroll
  for (int kt = 0; kt < 8; ++kt) {
    f16x8 bf0[2], bf1[2];
#pragma unroll
    for (int ct = 0; ct < 2; ++ct) {
      const int col = colB + ct * 16 + m;
      bf0[ct] = *(const f16x8*)&Wla0[((col * 8 + kt) << 5) + q * 8];
      bf1[ct] = *(const f16x8*)&Wla1[((col * 8 + kt) << 5) + q * 8];
    }
#pragma unroll
    for (int rt = 0; rt < 4; ++rt) {
      const f16x8 af = *(const f16x8*)&xso[rt * 16 + m][kt * 32 + q * 8];
#pragma unroll
      for (int ct = 0; ct < 2; ++ct)
        acc[rt][ct] = __builtin_amdgcn_mfma_f32_16x16x32_f16(
            af, rt == 0 ? bf0[ct] : bf1[ct], acc[rt][ct], 0, 0, 0);
    }
  }
  __syncthreads();  // all xso reads done before ost (alias) is written

#pragma unroll
  for (int rt = 0; rt < 4; ++rt) {
#pragma unroll
    for (int reg = 0; reg < 4; ++reg) {
      const int rloc = rt * 16 + q * 4 + reg;
#pragma unroll
      for (int ct = 0; ct < 2; ++ct) {
        const int v = colB + ct * 16 + m;
        if (rt == 0) {
          ost[rloc][v * 4] = acc[rt][ct][reg] * dens[rloc];
        } else {
          const int rr = rloc - 16;
          const int nn = rr / 3, kc = rr - nn * 3;
          ost[nn][v * 4 + 1 + kc] = acc[rt][ct][reg] * dens[nn];
        }
      }
    }
  }
  __syncthreads();
  for (int i = t; i < 2048; i += 256) {
    const int nn = i >> 7, pos = i & 127;
    *(float4*)&out[(size_t)(n0 + nn) * 512 + pos * 4] =
        *(const float4*)&ost[nn][pos * 4];
  }
}

// ---------------------------------------------------------------------------
extern "C" void kernel_launch(void* const* d_in, const int* in_sizes, int n_in,
                              void* d_out, int out_size, void* d_ws, size_t ws_size,
                              hipStream_t stream) {
  const float* node_attrs = (const float*)d_in[0];
  const float* node_feats = (const float*)d_in[1];
  const float* edge_attrs = (const float*)d_in[2];
  const float* edge_feats = (const float*)d_in[3];
  const int*   edge_index = (const int*)d_in[4];
  const float* W_up0 = (const float*)d_in[5];
  const float* W_up1 = (const float*)d_in[6];
  const float* R0 = (const float*)d_in[7];
  const float* R1 = (const float*)d_in[8];
  const float* R2 = (const float*)d_in[9];
  const float* R3 = (const float*)d_in[10];
  const float* Wd  = (const float*)d_in[11];
  const float* Wl0 = (const float*)d_in[12];
  const float* Wl1 = (const float*)d_in[13];
  const float* Ws0 = (const float*)d_in[14];
  const float* Ws1 = (const float*)d_in[15];
  float* out = (float*)d_out;

  __half* Hh = (__half*)d_ws;
  float* M = (float*)d_ws + (size_t)N_NODES * 512;
  float* density = M + (size_t)N_NODES * 1024;
  int* counts  = (int*)(density + 10000);
  int* offsets = counts + 10016;
  int* cursor  = offsets + 10016;
  int* snd_s   = cursor + 10016;
  int* rcv_s   = snd_s + N_EDGES;
  float* ea_s  = (float*)(rcv_s + N_EDGES);
  unsigned short* Bsw0 = (unsigned short*)(ea_s + (size_t)N_EDGES * 4);
  unsigned short* Bsw1 = Bsw0 + 1280 * 128;
  unsigned short* R1a  = Bsw1 + 1280 * 128;
  unsigned short* R2a  = R1a + 64 * 64;
  unsigned short* R3a  = R2a + 64 * 64;
  unsigned short* Wua0 = R3a + 64 * 512;
  unsigned short* Wua1 = Wua0 + 128 * 128;
  unsigned short* Wla0 = Wua1 + 128 * 128;
  unsigned short* Wla1 = Wla0 + 256 * 128;
  float* ef_s  = (float*)(Wla1 + 256 * 128);

  hipMemsetAsync(M, 0, ((size_t)N_NODES * 1024 + 10000 + 10016) * sizeof(float),
                 stream);

  k_prep<<<1684, 256, 0, stream>>>(Ws0, Ws1, Bsw0, Bsw1, R1, R1a, R2, R2a, R3,
                                   R3a, W_up0, Wua0, W_up1, Wua1, Wl0, Wla0,
                                   Wl1, Wla1, edge_index, counts);
  k_node_mfma<<<N_NODES / 16, 256, 0, stream>>>(node_feats, Wua0, Wua1, Hh);
  k_scan<<<1, 1024, 0, stream>>>(counts, offsets, cursor);
  k_scatter<<<(N_EDGES + 255) / 256, 256, 0, stream>>>(
      edge_index, edge_attrs, edge_feats, cursor, snd_s, rcv_s, ea_s, ef_s);
  k_mlp_msg<<<N_EDGES / 128, 256, 0, stream>>>(ef_s, ea_s, snd_s, rcv_s,
                                               offsets, R0, R1a, R2a, R3a, Wd,
                                               Hh, M, density);
  k_out_mfma<<<N_NODES / 16, 256, 0, stream>>>(M, density, Wla0, Wla1, out);
  k_skip_mfma<<<157 + 469, 256, 0, stream>>>(node_feats, node_attrs, Bsw0, Bsw1,
                                             out + (size_t)N_NODES * 512);
}

// Round 10
// 271.994 us; speedup vs baseline: 1.4387x; 1.0227x over previous
//
#include <hip/hip_runtime.h>
#include <hip/hip_bf16.h>
#include <hip/hip_fp16.h>

// Problem constants
#define N_NODES 10000
#define N_EDGES 128000
constexpr int C = 128;
constexpr int A = 10;

constexpr float INV_SQRT_C  = 0.08838834764831845f;   // 1/sqrt(128)
constexpr float INV_SQRT_R  = 0.35355339059327373f;   // 1/sqrt(8)
constexpr float INV_SQRT_64 = 0.125f;                 // 1/sqrt(64)
constexpr float INV_SQRT_CA = 0.027950849718747374f;  // 1/sqrt(1280)
constexpr float INV_SQRT_2C = 0.0625f;                // 1/sqrt(256)
constexpr float INV_SQRT_3  = 0.57735026918962576f;

typedef short short8 __attribute__((ext_vector_type(8)));
typedef _Float16 f16x8 __attribute__((ext_vector_type(8)));
typedef _Float16 f16x2 __attribute__((ext_vector_type(2)));
typedef float f32x4 __attribute__((ext_vector_type(4)));

__device__ __forceinline__ float silu_f(float x) { return x / (1.0f + __expf(-x)); }

__device__ __forceinline__ void atomic_add_f32(float* p, float v) {
  __hip_atomic_fetch_add(p, v, __ATOMIC_RELAXED, __HIP_MEMORY_SCOPE_AGENT);
}

__device__ __forceinline__ unsigned short f2h(float f) {
  return __builtin_bit_cast(unsigned short, (_Float16)f);  // RNE
}

__device__ __forceinline__ unsigned int pk2h(float a, float b) {
  auto h = __builtin_amdgcn_cvt_pkrtz(a, b);  // __fp16 ext_vector(2)
  return __builtin_bit_cast(unsigned int, h);
}

__device__ __forceinline__ unsigned int pkmul_h2(unsigned int x, unsigned int y) {
  const f16x2 a = __builtin_bit_cast(f16x2, x), b = __builtin_bit_cast(f16x2, y);
  return __builtin_bit_cast(unsigned int, a * b);  // v_pk_mul_f16
}

__device__ __forceinline__ float4 h4tof4(uint2 v) {
  const __half2 lo = __builtin_bit_cast(__half2, v.x);
  const __half2 hi = __builtin_bit_cast(__half2, v.y);
  const float2 flo = __half22float2(lo), fhi = __half22float2(hi);
  return make_float4(flo.x, flo.y, fhi.x, fhi.y);
}

// ---------------------------------------------------------------------------
// cvtw_d: DST-MAJOR weight convert (K x N fp32 -> f16 operand swizzle).
// Each call handles d0, d0+1 (one coalesced uint store). Reads scattered 4B
// from L2-resident fp32 source (cheap); writes fully coalesced (the src-major
// version's 2B stores at 64B stride were the R4 anti-pattern).
// ---------------------------------------------------------------------------
__device__ __forceinline__ void cvtw_d(const float* __restrict__ src,
                                       unsigned short* __restrict__ dst,
                                       int d0, int N, int lgKT) {
  unsigned int w = 0;
#pragma unroll
  for (int j = 0; j < 2; ++j) {
    const int d = d0 + j;
    const int kl = d & 31;
    const int kb = (d >> 5) & ((1 << lgKT) - 1);
    const int n = d >> (5 + lgKT);
    const int k = kb * 32 + kl;
    w |= (unsigned int)f2h(src[k * N + n]) << (16 * j);
  }
  *(unsigned int*)&dst[d0] = w;
}

// ---------------------------------------------------------------------------
// k_prep (dst-major converts + histogram):
//  b [0,320):    B0/B1 skip-GEMM operands (k'=a*128+u permuted), dst-major
//  b [320,336):  R1a, R2a (KT=2)
//  b [336,400):  R3a (N=512, KT=2)
//  b [400,464):  Wua0, Wua1 (KT=4)
//  b [464,592):  Wla0, Wla1 (KT=8)
//  b [592,1092): edge histogram
// ---------------------------------------------------------------------------
__global__ __launch_bounds__(256) void k_prep(
    const float* __restrict__ W0, const float* __restrict__ W1,
    unsigned short* __restrict__ B0, unsigned short* __restrict__ B1,
    const float* __restrict__ R1, unsigned short* __restrict__ R1a,
    const float* __restrict__ R2, unsigned short* __restrict__ R2a,
    const float* __restrict__ R3, unsigned short* __restrict__ R3a,
    const float* __restrict__ Wu0, unsigned short* __restrict__ Wua0,
    const float* __restrict__ Wu1, unsigned short* __restrict__ Wua1,
    const float* __restrict__ Wl0, unsigned short* __restrict__ Wla0,
    const float* __restrict__ Wl1, unsigned short* __restrict__ Wla1,
    const int* __restrict__ eidx, int* __restrict__ counts) {
  const int b = blockIdx.x, t = threadIdx.x;
  if (b < 320) {
    // B operand dst-major: dst = ((kp>>5)*128+col)*32 + (kp&31), kp=a*128+u,
    // source k = u*10+a. Inverse: kl=d&31, col=(d>>5)&127, kb=d>>12.
    const int d0 = (b * 256 + t) * 2;
    unsigned int w0 = 0, w1 = 0;
#pragma unroll
    for (int j = 0; j < 2; ++j) {
      const int d = d0 + j;
      const int kl = d & 31;
      const int col = (d >> 5) & 127;
      const int kb = d >> 12;
      const int kp = kb * 32 + kl;
      const int a = kp >> 7, u = kp & 127;
      const int src = (u * 10 + a) * 128 + col;
      w0 |= (unsigned int)f2h(W0[src]) << (16 * j);
      w1 |= (unsigned int)f2h(W1[src]) << (16 * j);
    }
    *(unsigned int*)&B0[d0] = w0;
    *(unsigned int*)&B1[d0] = w1;
  } else if (b < 328) {
    cvtw_d(R1, R1a, ((b - 320) * 256 + t) * 2, 64, 1);
  } else if (b < 336) {
    cvtw_d(R2, R2a, ((b - 328) * 256 + t) * 2, 64, 1);
  } else if (b < 400) {
    cvtw_d(R3, R3a, ((b - 336) * 256 + t) * 2, 512, 1);
  } else if (b < 432) {
    cvtw_d(Wu0, Wua0, ((b - 400) * 256 + t) * 2, 128, 2);
  } else if (b < 464) {
    cvtw_d(Wu1, Wua1, ((b - 432) * 256 + t) * 2, 128, 2);
  } else if (b < 528) {
    cvtw_d(Wl0, Wla0, ((b - 464) * 256 + t) * 2, 128, 3);
  } else if (b < 592) {
    cvtw_d(Wl1, Wla1, ((b - 528) * 256 + t) * 2, 128, 3);
  } else {
    const int e = (b - 592) * 256 + t;
    if (e < N_EDGES) atomicAdd(&counts[eidx[N_EDGES + e]], 1);
  }
}

// ---------------------------------------------------------------------------
// k_node_mfma (R9-proven): H = node-up GEMM via f16 MFMA.
// ---------------------------------------------------------------------------
__global__ __launch_bounds__(256) void k_node_mfma(
    const float* __restrict__ nf, const unsigned short* __restrict__ Wua0,
    const unsigned short* __restrict__ Wua1, __half* __restrict__ Hh) {
  __shared__ __align__(16) unsigned short xs[64][136];   // 17408 B
  __shared__ __align__(16) unsigned short hst[16][512];  // 16384 B
  const int t = threadIdx.x;
  const int wave = t >> 6, lane = t & 63, m = lane & 15, q = lane >> 4;
  const int n0 = blockIdx.x * 16;

  for (int i = t; i < 2048; i += 256) {
    const int nn = i >> 7, qq = (i & 127) * 4;
    const float4 v = *(const float4*)&nf[(size_t)(n0 + nn) * 512 + qq];
    const float vals[4] = {v.x, v.y, v.z, v.w};
    if (qq < 128) {
#pragma unroll
      for (int j = 0; j < 4; ++j) xs[nn][qq + j] = f2h(vals[j]);
    } else {
#pragma unroll
      for (int j = 0; j < 4; ++j) {
        const int r = qq + j - 128;
        const int u = r / 3, kc = r - u * 3;
        xs[16 + nn * 3 + kc][u] = f2h(vals[j]);
      }
    }
  }
  __syncthreads();

  const int colB = wave * 32;
  f32x4 acc[4][2];
#pragma unroll
  for (int rt = 0; rt < 4; ++rt)
#pragma unroll
    for (int ct = 0; ct < 2; ++ct) acc[rt][ct] = (f32x4){0.f, 0.f, 0.f, 0.f};

#pragma unroll
  for (int kt = 0; kt < 4; ++kt) {
    f16x8 bf0[2], bf1[2];
#pragma unroll
    for (int ct = 0; ct < 2; ++ct) {
      const int col = colB + ct * 16 + m;
      bf0[ct] = *(const f16x8*)&Wua0[((col * 4 + kt) << 5) + q * 8];
      bf1[ct] = *(const f16x8*)&Wua1[((col * 4 + kt) << 5) + q * 8];
    }
#pragma unroll
    for (int rt = 0; rt < 4; ++rt) {
      const f16x8 af = *(const f16x8*)&xs[rt * 16 + m][kt * 32 + q * 8];
#pragma unroll
      for (int ct = 0; ct < 2; ++ct)
        acc[rt][ct] = __builtin_amdgcn_mfma_f32_16x16x32_f16(
            af, rt == 0 ? bf0[ct] : bf1[ct], acc[rt][ct], 0, 0, 0);
    }
  }

#pragma unroll
  for (int rt = 0; rt < 4; ++rt) {
#pragma unroll
    for (int reg = 0; reg < 4; ++reg) {
      const int rloc = rt * 16 + q * 4 + reg;
#pragma unroll
      for (int ct = 0; ct < 2; ++ct) {
        const int v = colB + ct * 16 + m;
        const unsigned short hv = f2h(acc[rt][ct][reg] * INV_SQRT_C);
        if (rt == 0) {
          hst[rloc][v * 4] = hv;
        } else {
          const int rr = rloc - 16;
          const int nn = rr / 3, kc = rr - nn * 3;
          hst[nn][v * 4 + 1 + kc] = hv;
        }
      }
    }
  }
  __syncthreads();
  for (int i = t; i < 2048; i += 256) {
    const int nn = i >> 7, pos = i & 127;
    *(uint2*)&Hh[(size_t)(n0 + nn) * 512 + pos * 4] =
        *(const uint2*)&hst[nn][pos * 4];
  }
}

// ---------------------------------------------------------------------------
// K2 v4 (R8-proven): sc GEMM, 2 K-steps/phase (20 barriers) + cross-phase
// bfrag prefetch.
// ---------------------------------------------------------------------------
__global__ __launch_bounds__(256) void k_skip_mfma(
    const float* __restrict__ nf, const float* __restrict__ attrs,
    const unsigned short* __restrict__ B0, const unsigned short* __restrict__ B1,
    float* __restrict__ out_sc) {
  __shared__ __align__(16) unsigned short xs[64][136];       // 17408 B
  __shared__ float at[64][10];                               // 2560 B
  __shared__ __align__(16) unsigned short zs[2][2][64][40];  // 20480 B

  const int t = threadIdx.x;
  const int wave = t >> 6, lane = t & 63;
  const bool isG0 = blockIdx.x < 157;
  const int r0 = isG0 ? blockIdx.x * 64 : (blockIdx.x - 157) * 64;
  const int rcount = isG0 ? 10000 : 30000;
  const unsigned short* __restrict__ Bsw = isG0 ? B0 : B1;

  for (int idx = t; idx < 64 * 128; idx += 256) {
    const int i = idx >> 7, u = idx & 127;
    const int r = r0 + i;
    float v = 0.f;
    if (r < rcount) {
      if (isG0) v = nf[(size_t)r * 512 + u];
      else {
        const int n = r / 3, kc = r - n * 3;
        v = nf[(size_t)n * 512 + 128 + u * 3 + kc];
      }
    }
    xs[i][u] = f2h(v);
  }
  for (int idx = t; idx < 640; idx += 256) {
    const int i = idx / 10, a = idx - (idx / 10) * 10;
    const int r = r0 + i;
    float v = 0.f;
    if (r < rcount) v = attrs[(size_t)(isG0 ? r : r / 3) * 10 + a];
    at[i][a] = v;
  }
  __syncthreads();

  const int m = lane & 15, q = lane >> 4;
  const int colB = wave * 32;
  const int rr = t >> 2;
  const int off = (t & 3) * 8;

  unsigned int atr2[10];
#pragma unroll
  for (int a = 0; a < 10; ++a) {
    const unsigned int h = f2h(at[rr][a]);
    atr2[a] = h | (h << 16);
  }

  f32x4 acc[4][2];
#pragma unroll
  for (int rt = 0; rt < 4; ++rt)
#pragma unroll
    for (int ct = 0; ct < 2; ++ct) acc[rt][ct] = (f32x4){0.f, 0.f, 0.f, 0.f};

  // prologue: prefetch bfrag for phase 0 (kt = 0, 1)
  f16x8 bf[2][2];
#pragma unroll
  for (int sub = 0; sub < 2; ++sub)
#pragma unroll
    for (int ct = 0; ct < 2; ++ct)
      bf[sub][ct] = *(const f16x8*)&Bsw[(size_t)(sub * 128 + colB + ct * 16 + m) * 32 + q * 8];

#pragma unroll
  for (int a = 0; a < 10; ++a) {
    const unsigned int av2 = atr2[a];
#pragma unroll
    for (int pp = 0; pp < 2; ++pp) {
      const int p = a * 2 + pp;
      const int buf = p & 1;
#pragma unroll
      for (int sub = 0; sub < 2; ++sub) {
        const int kk = 2 * pp + sub;
        const uint4 xv = *(const uint4*)&xs[rr][kk * 32 + off];
        uint4 z;
        z.x = pkmul_h2(xv.x, av2);
        z.y = pkmul_h2(xv.y, av2);
        z.z = pkmul_h2(xv.z, av2);
        z.w = pkmul_h2(xv.w, av2);
        *(uint4*)&zs[buf][sub][rr][off] = z;
      }
      __syncthreads();

      f16x8 bfn[2][2];
      if (p < 19) {
        const int ktn = (p + 1) * 2;
#pragma unroll
        for (int sub = 0; sub < 2; ++sub)
#pragma unroll
          for (int ct = 0; ct < 2; ++ct)
            bfn[sub][ct] = *(const f16x8*)&Bsw[(size_t)((ktn + sub) * 128 + colB + ct * 16 + m) * 32 + q * 8];
      }

#pragma unroll
      for (int sub = 0; sub < 2; ++sub) {
#pragma unroll
        for (int rt = 0; rt < 4; ++rt) {
          const f16x8 afrag = *(const f16x8*)&zs[buf][sub][rt * 16 + m][q * 8];
#pragma unroll
          for (int ct = 0; ct < 2; ++ct)
            acc[rt][ct] = __builtin_amdgcn_mfma_f32_16x16x32_f16(
                afrag, bf[sub][ct], acc[rt][ct], 0, 0, 0);
        }
      }
      bf[0][0] = bfn[0][0]; bf[0][1] = bfn[0][1];
      bf[1][0] = bfn[1][0]; bf[1][1] = bfn[1][1];
    }
  }

#pragma unroll
  for (int rt = 0; rt < 4; ++rt) {
#pragma unroll
    for (int reg = 0; reg < 4; ++reg) {
      const int rloc = rt * 16 + q * 4 + reg;
      const int r = r0 + rloc;
      if (r < rcount) {
#pragma unroll
        for (int ct = 0; ct < 2; ++ct) {
          const int v = colB + ct * 16 + m;
          const float val = acc[rt][ct][reg] * INV_SQRT_CA;
          if (isG0) {
            out_sc[(size_t)r * 512 + v] = val;
          } else {
            const int n = r / 3, kc = r - (r / 3) * 3;
            out_sc[(size_t)n * 512 + 128 + v * 3 + kc] = val;
          }
        }
      }
    }
  }
}

// ---------------------------------------------------------------------------
// Sort-by-receiver: scan -> scatter. Scatter now writes ONLY perm[pos]=e
// (4B random write vs the old 48B physical reorder); k_mlp_msg gathers the
// edge data through perm from the L2/L3-resident original arrays.
// ---------------------------------------------------------------------------
__global__ __launch_bounds__(1024) void k_scan(const int* __restrict__ counts,
                                               int* __restrict__ offsets,
                                               int* __restrict__ cursor) {
  __shared__ int part[1024];
  const int t = threadIdx.x;
  int local[10];
  int s = 0;
#pragma unroll
  for (int i = 0; i < 10; ++i) {
    const int idx = t * 10 + i;
    const int c = (idx < N_NODES) ? counts[idx] : 0;
    local[i] = s;
    s += c;
  }
  part[t] = s;
  __syncthreads();
  for (int off = 1; off < 1024; off <<= 1) {
    const int add = (t >= off) ? part[t - off] : 0;
    __syncthreads();
    part[t] += add;
    __syncthreads();
  }
  const int pre = (t > 0) ? part[t - 1] : 0;
#pragma unroll
  for (int i = 0; i < 10; ++i) {
    const int idx = t * 10 + i;
    if (idx < N_NODES) {
      const int o = pre + local[i];
      offsets[idx] = o;
      cursor[idx] = o;
    }
  }
  if (t == 1023) offsets[N_NODES] = part[1023];
}

__global__ __launch_bounds__(256) void k_scatter(
    const int* __restrict__ eidx, int* __restrict__ cursor,
    int* __restrict__ perm) {
  const int e = blockIdx.x * 256 + threadIdx.x;
  if (e < N_EDGES) {
    const int r = eidx[N_EDGES + e];
    const int pos = atomicAdd(&cursor[r], 1);
    perm[pos] = e;
  }
}

// ---------------------------------------------------------------------------
// K3 (R5-proven core): edge MLP + messages + segmented reduce.
// v6: staging gathers through perm (sorted edge-id list) from the ORIGINAL
// ef/ea/eidx arrays (L2/L3-resident, same class as Hh gathers) — the 48B
// physical reorder in scatter is gone.
// ---------------------------------------------------------------------------
__global__ __launch_bounds__(256, 4) void k_mlp_msg(
    const float* __restrict__ ef_g, const float* __restrict__ ea_g,
    const int* __restrict__ eidx, const int* __restrict__ perm,
    const int* __restrict__ offsets,
    const float* __restrict__ R0, const unsigned short* __restrict__ R1a,
    const unsigned short* __restrict__ R2a, const unsigned short* __restrict__ R3a,
    const float* __restrict__ Wd, const __half* __restrict__ Hh,
    float* __restrict__ M, float* __restrict__ density) {
  __shared__ __align__(16) unsigned short actA[128][72];  // 18 KB
  __shared__ __align__(16) unsigned char uni[18432];      // 18 KB union
  __shared__ __align__(16) float ys[128][4];              // 2 KB
  __shared__ __align__(16) int sn[144];                   // 576 B
  __shared__ __align__(16) int rc[128];                   // 512 B
  float (*efs)[9] = (float (*)[9]) & uni[0];
  unsigned short (*actB)[72] = (unsigned short (*)[72]) & uni[0];
  __half (*wls2)[536] = (__half (*)[536]) & uni[0];

  const int t = threadIdx.x;
  const int wave = t >> 6, lane = t & 63, m = lane & 15, q = lane >> 4;
  const int e0 = blockIdx.x * 128;

  // gather-staging via perm: ef (2 threads/edge), ea/snd/rcv (1 thread/edge)
  {
    const int pm = perm[e0 + (t >> 1)];
    const float4 v = *(const float4*)&ef_g[(size_t)pm * 8 + (t & 1) * 4];
    const int e = t >> 1, c0 = (t & 1) * 4;
    efs[e][c0] = v.x; efs[e][c0 + 1] = v.y;
    efs[e][c0 + 2] = v.z; efs[e][c0 + 3] = v.w;
  }
  if (t < 128) {
    const int pe = perm[e0 + t];
    *(float4*)&ys[t][0] = ((const float4*)ea_g)[pe];
    sn[t] = eidx[pe];
    rc[t] = eidx[N_EDGES + pe];
  } else if (t < 144) {
    sn[t] = 0;
  }
  __syncthreads();

  const int u = t & 127, half = t >> 7;
  const size_t ucol = (size_t)(u << 2);
  uint2 hA[4], hB[4];
#pragma unroll
  for (int j = 0; j < 4; ++j)
    hA[j] = *(const uint2*)&Hh[(size_t)sn[j] * 512 + ucol];
#pragma unroll
  for (int j = 0; j < 4; ++j)
    hB[j] = *(const uint2*)&Hh[(size_t)sn[4 + j] * 512 + ucol];

  if (t < 128) {
    float s = 0.f;
#pragma unroll
    for (int i = 0; i < 8; ++i) s = fmaf(efs[t][i], Wd[i], s);
    s *= INV_SQRT_R;
    atomic_add_f32(&density[rc[t]], tanhf(s * s));
  }

  // L1
  {
    const int e = t & 127, j0 = (t >> 7) * 32;
    float a[32] = {};
#pragma unroll
    for (int i = 0; i < 8; ++i) {
      const float v = efs[e][i];
#pragma unroll
      for (int jj = 0; jj < 32; ++jj)
        a[jj] = fmaf(v, R0[i * 64 + j0 + jj], a[jj]);
    }
#pragma unroll
    for (int g = 0; g < 8; ++g) {
      uint2 pk;
      pk.x = pk2h(silu_f(a[4 * g] * INV_SQRT_R), silu_f(a[4 * g + 1] * INV_SQRT_R));
      pk.y = pk2h(silu_f(a[4 * g + 2] * INV_SQRT_R), silu_f(a[4 * g + 3] * INV_SQRT_R));
      *(uint2*)&actA[e][j0 + g * 4] = pk;
    }
  }
  __syncthreads();

  // L2
  {
    const f16x8 af0 = *(const f16x8*)&R1a[(((wave * 16 + m) * 2 + 0) << 5) + q * 8];
    const f16x8 af1 = *(const f16x8*)&R1a[(((wave * 16 + m) * 2 + 1) << 5) + q * 8];
#pragma unroll
    for (int et = 0; et < 8; ++et) {
      const f16x8 bf0 = *(const f16x8*)&actA[et * 16 + m][q * 8];
      const f16x8 bf1 = *(const f16x8*)&actA[et * 16 + m][32 + q * 8];
      f32x4 c = {0.f, 0.f, 0.f, 0.f};
      c = __builtin_amdgcn_mfma_f32_16x16x32_f16(af0, bf0, c, 0, 0, 0);
      c = __builtin_amdgcn_mfma_f32_16x16x32_f16(af1, bf1, c, 0, 0, 0);
      uint2 pk;
      pk.x = pk2h(silu_f(c[0] * INV_SQRT_64), silu_f(c[1] * INV_SQRT_64));
      pk.y = pk2h(silu_f(c[2] * INV_SQRT_64), silu_f(c[3] * INV_SQRT_64));
      *(uint2*)&actB[et * 16 + m][wave * 16 + q * 4] = pk;
    }
  }
  __syncthreads();

  // L3
  {
    const f16x8 af0 = *(const f16x8*)&R2a[(((wave * 16 + m) * 2 + 0) << 5) + q * 8];
    const f16x8 af1 = *(const f16x8*)&R2a[(((wave * 16 + m) * 2 + 1) << 5) + q * 8];
#pragma unroll
    for (int et = 0; et < 8; ++et) {
      const f16x8 bf0 = *(const f16x8*)&actB[et * 16 + m][q * 8];
      const f16x8 bf1 = *(const f16x8*)&actB[et * 16 + m][32 + q * 8];
      f32x4 c = {0.f, 0.f, 0.f, 0.f};
      c = __builtin_amdgcn_mfma_f32_16x16x32_f16(af0, bf0, c, 0, 0, 0);
      c = __builtin_amdgcn_mfma_f32_16x16x32_f16(af1, bf1, c, 0, 0, 0);
      uint2 pk;
      pk.x = pk2h(silu_f(c[0] * INV_SQRT_64), silu_f(c[1] * INV_SQRT_64));
      pk.y = pk2h(silu_f(c[2] * INV_SQRT_64), silu_f(c[3] * INV_SQRT_64));
      *(uint2*)&actA[et * 16 + m][wave * 16 + q * 4] = pk;
    }
  }
  __syncthreads();

  const int baseJ = (wave & 1) * 4 + (wave >> 1) * 16;
  f16x8 afL[4][2], afH[4][2];
#pragma unroll
  for (int i = 0; i < 4; ++i) {
#pragma unroll
    for (int kt = 0; kt < 2; ++kt) {
      const int JL = baseJ + i, JH = JL + 8;
      afL[i][kt] = *(const f16x8*)&R3a[(((JL * 16 + m) * 2 + kt) << 5) + q * 8];
      afH[i][kt] = *(const f16x8*)&R3a[(((JH * 16 + m) * 2 + kt) << 5) + q * 8];
    }
  }

  float a0 = 0.f, a1 = 0.f, a2 = 0.f, a3 = 0.f;
  int cur = rc[0];
  int s0c = offsets[cur], s1c = offsets[cur + 1];
  const int colx = (half ? 128 + u : u) * 2;

  auto flush = [&](int n, int s0, int s1) {
    float* Mp = &M[(size_t)n * 1024 + (half << 9) + (u << 2)];
    if (s0 >= e0 && s1 <= e0 + 128) {
      *(float4*)Mp = make_float4(a0, a1, a2, a3);
    } else {
      atomic_add_f32(Mp + 0, a0);
      atomic_add_f32(Mp + 1, a1);
      atomic_add_f32(Mp + 2, a2);
      atomic_add_f32(Mp + 3, a3);
    }
  };

  auto proc = [&](const uint2 hcur, unsigned int pr, const float4 yv, int n) {
    if (n != cur) {  // wave-uniform
      flush(cur, s0c, s1c);
      a0 = a1 = a2 = a3 = 0.f;
      cur = n;
      s0c = offsets[n];
      s1c = offsets[n + 1];
    }
    const float4 h4 = h4tof4(hcur);
    const __half2 ph = __builtin_bit_cast(__half2, pr);
    const float2 pw = __half22float2(ph);
    if (half == 0) {
      a0 = fmaf(pw.x * h4.x, yv.x, a0);
      const float c1 = pw.y * h4.x;
      a1 = fmaf(c1, yv.y, a1);
      a2 = fmaf(c1, yv.z, a2);
      a3 = fmaf(c1, yv.w, a3);
    } else {
      const float dt = h4.y * yv.y + h4.z * yv.z + h4.w * yv.w;
      a0 = fmaf(pw.y * dt, INV_SQRT_3, a0);
      const float c3 = pw.x * yv.x;
      a1 = fmaf(c3, h4.y, a1);
      a2 = fmaf(c3, h4.z, a2);
      a3 = fmaf(c3, h4.w, a3);
    }
  };

#define MSG_GROUP(G, HX)                                                    \
  {                                                                         \
    const int gb = ch * 16 + (G) * 4;                                       \
    unsigned int prv[4];                                                    \
    float4 yv4[4];                                                          \
    _Pragma("unroll") for (int j = 0; j < 4; ++j)                           \
        prv[j] = *(const unsigned int*)&wls2[(G) * 4 + j][colx];            \
    _Pragma("unroll") for (int j = 0; j < 4; ++j)                           \
        yv4[j] = *(const float4*)&ys[gb + j][0];                            \
    const int4 rc4 = *(const int4*)&rc[gb];                                 \
    proc(HX[0], prv[0], yv4[0], rc4.x);                                     \
    proc(HX[1], prv[1], yv4[1], rc4.y);                                     \
    proc(HX[2], prv[2], yv4[2], rc4.z);                                     \
    proc(HX[3], prv[3], yv4[3], rc4.w);                                     \
    const int4 sn4 = *(const int4*)&sn[gb + 8];                             \
    HX[0] = *(const uint2*)&Hh[(size_t)sn4.x * 512 + ucol];                 \
    HX[1] = *(const uint2*)&Hh[(size_t)sn4.y * 512 + ucol];                 \
    HX[2] = *(const uint2*)&Hh[(size_t)sn4.z * 512 + ucol];                 \
    HX[3] = *(const uint2*)&Hh[(size_t)sn4.w * 512 + ucol];                 \
  }

  // BARRIER-FREE chunk loop (wave w produces AND consumes wls2 [w*64,(w+1)*64))
#pragma unroll 1
  for (int ch = 0; ch < 8; ++ch) {
    {
      const f16x8 bf0 = *(const f16x8*)&actA[ch * 16 + m][q * 8];
      const f16x8 bf1 = *(const f16x8*)&actA[ch * 16 + m][32 + q * 8];
#pragma unroll
      for (int i = 0; i < 4; ++i) {
        f32x4 cL = {0.f, 0.f, 0.f, 0.f}, cH = {0.f, 0.f, 0.f, 0.f};
        cL = __builtin_amdgcn_mfma_f32_16x16x32_f16(afL[i][0], bf0, cL, 0, 0, 0);
        cL = __builtin_amdgcn_mfma_f32_16x16x32_f16(afL[i][1], bf1, cL, 0, 0, 0);
        cH = __builtin_amdgcn_mfma_f32_16x16x32_f16(afH[i][0], bf0, cH, 0, 0, 0);
        cH = __builtin_amdgcn_mfma_f32_16x16x32_f16(afH[i][1], bf1, cH, 0, 0, 0);
        uint4 pk;
        pk.x = pk2h(cL[0] * INV_SQRT_64, cH[0] * INV_SQRT_64);
        pk.y = pk2h(cL[1] * INV_SQRT_64, cH[1] * INV_SQRT_64);
        pk.z = pk2h(cL[2] * INV_SQRT_64, cH[2] * INV_SQRT_64);
        pk.w = pk2h(cL[3] * INV_SQRT_64, cH[3] * INV_SQRT_64);
        const int JL = baseJ + i;
        const int pidx0 = ((JL < 8) ? JL * 16 : (JL - 16) * 16 + 128) + q * 4;
        *(uint4*)&wls2[m][pidx0 * 2] = pk;
      }
    }
    MSG_GROUP(0, hA)
    MSG_GROUP(1, hB)
    MSG_GROUP(2, hA)
    MSG_GROUP(3, hB)
  }
#undef MSG_GROUP
  flush(cur, s0c, s1c);
}

// ---------------------------------------------------------------------------
// k_out_mfma (R9-proven): out = M@Wl via f16 MFMA.
// ---------------------------------------------------------------------------
__global__ __launch_bounds__(256) void k_out_mfma(
    const float* __restrict__ M, const float* __restrict__ density,
    const unsigned short* __restrict__ Wla0,
    const unsigned short* __restrict__ Wla1, float* __restrict__ out) {
  __shared__ __align__(16) unsigned char sm[64 * 264 * 2];  // 33792 B union
  __shared__ float dens[16];
  unsigned short (*xso)[264] = (unsigned short (*)[264])sm;  // [64][264] f16
  float (*ost)[512] = (float (*)[512])sm;                    // 32768 B
  const int t = threadIdx.x;
  const int wave = t >> 6, lane = t & 63, m = lane & 15, q = lane >> 4;
  const int n0 = blockIdx.x * 16;

  if (t < 16) dens[t] = INV_SQRT_2C / (density[n0 + t] + 1.0f);

  const float4* Mf4 = (const float4*)&M[(size_t)n0 * 1024];
  for (int i = t; i < 4096; i += 256) {
    const float4 v = Mf4[i];
    const int nn = i >> 8, p = i & 255;
    xso[nn][p] = f2h(v.x);
    const int rb = 16 + nn * 3;
    xso[rb][p] = f2h(v.y);
    xso[rb + 1][p] = f2h(v.z);
    xso[rb + 2][p] = f2h(v.w);
  }
  __syncthreads();

  const int colB = wave * 32;
  f32x4 acc[4][2];
#pragma unroll
  for (int rt = 0; rt < 4; ++rt)
#pragma unroll
    for (int ct = 0; ct < 2; ++ct) acc[rt][ct] = (f32x4){0.f, 0.f, 0.f, 0.f};

#pragma unroll
  for (int kt = 0; kt < 8; ++kt) {
    f16x8 bf0[2], bf1[2];
#pragma unroll
    for (int ct = 0; ct < 2; ++ct) {
      const int col = colB + ct * 16 + m;
      bf0[ct] = *(const f16x8*)&Wla0[((col * 8 + kt) << 5) + q * 8];
      bf1[ct] = *(const f16x8*)&Wla1[((col * 8 + kt) << 5) + q * 8];
    }
#pragma unroll
    for (int rt = 0; rt < 4; ++rt) {
      const f16x8 af = *(const f16x8*)&xso[rt * 16 + m][kt * 32 + q * 8];
#pragma unroll
      for (int ct = 0; ct < 2; ++ct)
        acc[rt][ct] = __builtin_amdgcn_mfma_f32_16x16x32_f16(
            af, rt == 0 ? bf0[ct] : bf1[ct], acc[rt][ct], 0, 0, 0);
    }
  }
  __syncthreads();  // all xso reads done before ost (alias) is written

#pragma unroll
  for (int rt = 0; rt < 4; ++rt) {
#pragma unroll
    for (int reg = 0; reg < 4; ++reg) {
      const int rloc = rt * 16 + q * 4 + reg;
#pragma unroll
      for (int ct = 0; ct < 2; ++ct) {
        const int v = colB + ct * 16 + m;
        if (rt == 0) {
          ost[rloc][v * 4] = acc[rt][ct][reg] * dens[rloc];
        } else {
          const int rr = rloc - 16;
          const int nn = rr / 3, kc = rr - nn * 3;
          ost[nn][v * 4 + 1 + kc] = acc[rt][ct][reg] * dens[nn];
        }
      }
    }
  }
  __syncthreads();
  for (int i = t; i < 2048; i += 256) {
    const int nn = i >> 7, pos = i & 127;
    *(float4*)&out[(size_t)(n0 + nn) * 512 + pos * 4] =
        *(const float4*)&ost[nn][pos * 4];
  }
}

// ---------------------------------------------------------------------------
extern "C" void kernel_launch(void* const* d_in, const int* in_sizes, int n_in,
                              void* d_out, int out_size, void* d_ws, size_t ws_size,
                              hipStream_t stream) {
  const float* node_attrs = (const float*)d_in[0];
  const float* node_feats = (const float*)d_in[1];
  const float* edge_attrs = (const float*)d_in[2];
  const float* edge_feats = (const float*)d_in[3];
  const int*   edge_index = (const int*)d_in[4];
  const float* W_up0 = (const float*)d_in[5];
  const float* W_up1 = (const float*)d_in[6];
  const float* R0 = (const float*)d_in[7];
  const float* R1 = (const float*)d_in[8];
  const float* R2 = (const float*)d_in[9];
  const float* R3 = (const float*)d_in[10];
  const float* Wd  = (const float*)d_in[11];
  const float* Wl0 = (const float*)d_in[12];
  const float* Wl1 = (const float*)d_in[13];
  const float* Ws0 = (const float*)d_in[14];
  const float* Ws1 = (const float*)d_in[15];
  float* out = (float*)d_out;

  // Workspace: H | M | density | counts | offsets | cursor | perm |
  // Bsw0 | Bsw1 | R1a | R2a | R3a | Wua0 | Wua1 | Wla0 | Wla1
  __half* Hh = (__half*)d_ws;
  float* M = (float*)d_ws + (size_t)N_NODES * 512;
  float* density = M + (size_t)N_NODES * 1024;
  int* counts  = (int*)(density + 10000);
  int* offsets = counts + 10016;
  int* cursor  = offsets + 10016;
  int* perm    = cursor + 10016;
  unsigned short* Bsw0 = (unsigned short*)(perm + N_EDGES);
  unsigned short* Bsw1 = Bsw0 + 1280 * 128;
  unsigned short* R1a  = Bsw1 + 1280 * 128;
  unsigned short* R2a  = R1a + 64 * 64;
  unsigned short* R3a  = R2a + 64 * 64;
  unsigned short* Wua0 = R3a + 64 * 512;
  unsigned short* Wua1 = Wua0 + 128 * 128;
  unsigned short* Wla0 = Wua1 + 128 * 128;
  unsigned short* Wla1 = Wla0 + 256 * 128;

  hipMemsetAsync(M, 0, ((size_t)N_NODES * 1024 + 10000 + 10016) * sizeof(float),
                 stream);

  k_prep<<<1092, 256, 0, stream>>>(Ws0, Ws1, Bsw0, Bsw1, R1, R1a, R2, R2a, R3,
                                   R3a, W_up0, Wua0, W_up1, Wua1, Wl0, Wla0,
                                   Wl1, Wla1, edge_index, counts);
  k_node_mfma<<<N_NODES / 16, 256, 0, stream>>>(node_feats, Wua0, Wua1, Hh);
  k_scan<<<1, 1024, 0, stream>>>(counts, offsets, cursor);
  k_scatter<<<(N_EDGES + 255) / 256, 256, 0, stream>>>(edge_index, cursor,
                                                       perm);
  k_mlp_msg<<<N_EDGES / 128, 256, 0, stream>>>(edge_feats, edge_attrs,
                                               edge_index, perm, offsets, R0,
                                               R1a, R2a, R3a, Wd, Hh, M,
                                               density);
  k_out_mfma<<<N_NODES / 16, 256, 0, stream>>>(M, density, Wla0, Wla1, out);
  k_skip_mfma<<<157 + 469, 256, 0, stream>>>(node_feats, node_attrs, Bsw0, Bsw1,
                                             out + (size_t)N_NODES * 512);
}

// Round 11
// 271.730 us; speedup vs baseline: 1.4401x; 1.0010x over previous
//
#include <hip/hip_runtime.h>
#include <hip/hip_bf16.h>
#include <hip/hip_fp16.h>

// Problem constants
#define N_NODES 10000
#define N_EDGES 128000
constexpr int C = 128;
constexpr int A = 10;

constexpr float INV_SQRT_C  = 0.08838834764831845f;   // 1/sqrt(128)
constexpr float INV_SQRT_R  = 0.35355339059327373f;   // 1/sqrt(8)
constexpr float INV_SQRT_64 = 0.125f;                 // 1/sqrt(64)
constexpr float INV_SQRT_CA = 0.027950849718747374f;  // 1/sqrt(1280)
constexpr float INV_SQRT_2C = 0.0625f;                // 1/sqrt(256)
constexpr float INV_SQRT_3  = 0.57735026918962576f;

typedef short short8 __attribute__((ext_vector_type(8)));
typedef _Float16 f16x8 __attribute__((ext_vector_type(8)));
typedef _Float16 f16x2 __attribute__((ext_vector_type(2)));
typedef float f32x4 __attribute__((ext_vector_type(4)));

__device__ __forceinline__ float silu_f(float x) { return x / (1.0f + __expf(-x)); }

__device__ __forceinline__ void atomic_add_f32(float* p, float v) {
  __hip_atomic_fetch_add(p, v, __ATOMIC_RELAXED, __HIP_MEMORY_SCOPE_AGENT);
}

__device__ __forceinline__ unsigned short f2h(float f) {
  return __builtin_bit_cast(unsigned short, (_Float16)f);  // RNE
}

__device__ __forceinline__ unsigned int pk2h(float a, float b) {
  auto h = __builtin_amdgcn_cvt_pkrtz(a, b);  // __fp16 ext_vector(2)
  return __builtin_bit_cast(unsigned int, h);
}

__device__ __forceinline__ unsigned int pkmul_h2(unsigned int x, unsigned int y) {
  const f16x2 a = __builtin_bit_cast(f16x2, x), b = __builtin_bit_cast(f16x2, y);
  return __builtin_bit_cast(unsigned int, a * b);  // v_pk_mul_f16
}

__device__ __forceinline__ float4 h4tof4(uint2 v) {
  const __half2 lo = __builtin_bit_cast(__half2, v.x);
  const __half2 hi = __builtin_bit_cast(__half2, v.y);
  const float2 flo = __half22float2(lo), fhi = __half22float2(hi);
  return make_float4(flo.x, flo.y, fhi.x, fhi.y);
}

// ---------------------------------------------------------------------------
// cvtw_d: DST-MAJOR weight convert (K x N fp32 -> f16 operand swizzle).
// ---------------------------------------------------------------------------
__device__ __forceinline__ void cvtw_d(const float* __restrict__ src,
                                       unsigned short* __restrict__ dst,
                                       int d0, int N, int lgKT) {
  unsigned int w = 0;
#pragma unroll
  for (int j = 0; j < 2; ++j) {
    const int d = d0 + j;
    const int kl = d & 31;
    const int kb = (d >> 5) & ((1 << lgKT) - 1);
    const int n = d >> (5 + lgKT);
    const int k = kb * 32 + kl;
    w |= (unsigned int)f2h(src[k * N + n]) << (16 * j);
  }
  *(unsigned int*)&dst[d0] = w;
}

// ---------------------------------------------------------------------------
// k_prep (dst-major converts + 64B edge-line packing + histogram):
//  b [0,320):     B0/B1 skip-GEMM operands (k'=a*128+u), dst-major
//  b [320,336):   R1a, R2a (KT=2)
//  b [336,400):   R3a (N=512, KT=2)
//  b [400,464):   Wua0, Wua1 (KT=4)
//  b [464,592):   Wla0, Wla1 (KT=8)
//  b [592,1092):  pack[e] = {ef[8] | ea[4] | sn, rc, 0, 0} -- ONE 64B line
//                 per edge so mlp's perm-gather fetches exactly one line
//                 (R10's 48B-at-3-addresses gather over-fetched +14MB).
//  b [1092,1592): edge histogram
// ---------------------------------------------------------------------------
__global__ __launch_bounds__(256) void k_prep(
    const float* __restrict__ W0, const float* __restrict__ W1,
    unsigned short* __restrict__ B0, unsigned short* __restrict__ B1,
    const float* __restrict__ R1, unsigned short* __restrict__ R1a,
    const float* __restrict__ R2, unsigned short* __restrict__ R2a,
    const float* __restrict__ R3, unsigned short* __restrict__ R3a,
    const float* __restrict__ Wu0, unsigned short* __restrict__ Wua0,
    const float* __restrict__ Wu1, unsigned short* __restrict__ Wua1,
    const float* __restrict__ Wl0, unsigned short* __restrict__ Wla0,
    const float* __restrict__ Wl1, unsigned short* __restrict__ Wla1,
    const float* __restrict__ ef_g, const float* __restrict__ ea_g,
    const int* __restrict__ eidx, float* __restrict__ pack,
    int* __restrict__ counts) {
  const int b = blockIdx.x, t = threadIdx.x;
  if (b < 320) {
    const int d0 = (b * 256 + t) * 2;
    unsigned int w0 = 0, w1 = 0;
#pragma unroll
    for (int j = 0; j < 2; ++j) {
      const int d = d0 + j;
      const int kl = d & 31;
      const int col = (d >> 5) & 127;
      const int kb = d >> 12;
      const int kp = kb * 32 + kl;
      const int a = kp >> 7, u = kp & 127;
      const int src = (u * 10 + a) * 128 + col;
      w0 |= (unsigned int)f2h(W0[src]) << (16 * j);
      w1 |= (unsigned int)f2h(W1[src]) << (16 * j);
    }
    *(unsigned int*)&B0[d0] = w0;
    *(unsigned int*)&B1[d0] = w1;
  } else if (b < 328) {
    cvtw_d(R1, R1a, ((b - 320) * 256 + t) * 2, 64, 1);
  } else if (b < 336) {
    cvtw_d(R2, R2a, ((b - 328) * 256 + t) * 2, 64, 1);
  } else if (b < 400) {
    cvtw_d(R3, R3a, ((b - 336) * 256 + t) * 2, 512, 1);
  } else if (b < 432) {
    cvtw_d(Wu0, Wua0, ((b - 400) * 256 + t) * 2, 128, 2);
  } else if (b < 464) {
    cvtw_d(Wu1, Wua1, ((b - 432) * 256 + t) * 2, 128, 2);
  } else if (b < 528) {
    cvtw_d(Wl0, Wla0, ((b - 464) * 256 + t) * 2, 128, 3);
  } else if (b < 592) {
    cvtw_d(Wl1, Wla1, ((b - 528) * 256 + t) * 2, 128, 3);
  } else if (b < 1092) {
    const int e = (b - 592) * 256 + t;
    const float4 p0 = ((const float4*)ef_g)[(size_t)e * 2];
    const float4 p1 = ((const float4*)ef_g)[(size_t)e * 2 + 1];
    const float4 p2 = ((const float4*)ea_g)[e];
    float4 p3;
    p3.x = __builtin_bit_cast(float, eidx[e]);
    p3.y = __builtin_bit_cast(float, eidx[N_EDGES + e]);
    p3.z = 0.f; p3.w = 0.f;
    float4* dst = (float4*)&pack[(size_t)e * 16];
    dst[0] = p0; dst[1] = p1; dst[2] = p2; dst[3] = p3;
  } else {
    const int e = (b - 1092) * 256 + t;
    if (e < N_EDGES) atomicAdd(&counts[eidx[N_EDGES + e]], 1);
  }
}

// ---------------------------------------------------------------------------
// k_node_mfma (R9-proven): H = node-up GEMM via f16 MFMA.
// ---------------------------------------------------------------------------
__global__ __launch_bounds__(256) void k_node_mfma(
    const float* __restrict__ nf, const unsigned short* __restrict__ Wua0,
    const unsigned short* __restrict__ Wua1, __half* __restrict__ Hh) {
  __shared__ __align__(16) unsigned short xs[64][136];   // 17408 B
  __shared__ __align__(16) unsigned short hst[16][512];  // 16384 B
  const int t = threadIdx.x;
  const int wave = t >> 6, lane = t & 63, m = lane & 15, q = lane >> 4;
  const int n0 = blockIdx.x * 16;

  for (int i = t; i < 2048; i += 256) {
    const int nn = i >> 7, qq = (i & 127) * 4;
    const float4 v = *(const float4*)&nf[(size_t)(n0 + nn) * 512 + qq];
    const float vals[4] = {v.x, v.y, v.z, v.w};
    if (qq < 128) {
#pragma unroll
      for (int j = 0; j < 4; ++j) xs[nn][qq + j] = f2h(vals[j]);
    } else {
#pragma unroll
      for (int j = 0; j < 4; ++j) {
        const int r = qq + j - 128;
        const int u = r / 3, kc = r - u * 3;
        xs[16 + nn * 3 + kc][u] = f2h(vals[j]);
      }
    }
  }
  __syncthreads();

  const int colB = wave * 32;
  f32x4 acc[4][2];
#pragma unroll
  for (int rt = 0; rt < 4; ++rt)
#pragma unroll
    for (int ct = 0; ct < 2; ++ct) acc[rt][ct] = (f32x4){0.f, 0.f, 0.f, 0.f};

#pragma unroll
  for (int kt = 0; kt < 4; ++kt) {
    f16x8 bf0[2], bf1[2];
#pragma unroll
    for (int ct = 0; ct < 2; ++ct) {
      const int col = colB + ct * 16 + m;
      bf0[ct] = *(const f16x8*)&Wua0[((col * 4 + kt) << 5) + q * 8];
      bf1[ct] = *(const f16x8*)&Wua1[((col * 4 + kt) << 5) + q * 8];
    }
#pragma unroll
    for (int rt = 0; rt < 4; ++rt) {
      const f16x8 af = *(const f16x8*)&xs[rt * 16 + m][kt * 32 + q * 8];
#pragma unroll
      for (int ct = 0; ct < 2; ++ct)
        acc[rt][ct] = __builtin_amdgcn_mfma_f32_16x16x32_f16(
            af, rt == 0 ? bf0[ct] : bf1[ct], acc[rt][ct], 0, 0, 0);
    }
  }

#pragma unroll
  for (int rt = 0; rt < 4; ++rt) {
#pragma unroll
    for (int reg = 0; reg < 4; ++reg) {
      const int rloc = rt * 16 + q * 4 + reg;
#pragma unroll
      for (int ct = 0; ct < 2; ++ct) {
        const int v = colB + ct * 16 + m;
        const unsigned short hv = f2h(acc[rt][ct][reg] * INV_SQRT_C);
        if (rt == 0) {
          hst[rloc][v * 4] = hv;
        } else {
          const int rr = rloc - 16;
          const int nn = rr / 3, kc = rr - nn * 3;
          hst[nn][v * 4 + 1 + kc] = hv;
        }
      }
    }
  }
  __syncthreads();
  for (int i = t; i < 2048; i += 256) {
    const int nn = i >> 7, pos = i & 127;
    *(uint2*)&Hh[(size_t)(n0 + nn) * 512 + pos * 4] =
        *(const uint2*)&hst[nn][pos * 4];
  }
}

// ---------------------------------------------------------------------------
// K2 v4 (R8-proven): sc GEMM, 2 K-steps/phase (20 barriers) + cross-phase
// bfrag prefetch.
// ---------------------------------------------------------------------------
__global__ __launch_bounds__(256) void k_skip_mfma(
    const float* __restrict__ nf, const float* __restrict__ attrs,
    const unsigned short* __restrict__ B0, const unsigned short* __restrict__ B1,
    float* __restrict__ out_sc) {
  __shared__ __align__(16) unsigned short xs[64][136];       // 17408 B
  __shared__ float at[64][10];                               // 2560 B
  __shared__ __align__(16) unsigned short zs[2][2][64][40];  // 20480 B

  const int t = threadIdx.x;
  const int wave = t >> 6, lane = t & 63;
  const bool isG0 = blockIdx.x < 157;
  const int r0 = isG0 ? blockIdx.x * 64 : (blockIdx.x - 157) * 64;
  const int rcount = isG0 ? 10000 : 30000;
  const unsigned short* __restrict__ Bsw = isG0 ? B0 : B1;

  for (int idx = t; idx < 64 * 128; idx += 256) {
    const int i = idx >> 7, u = idx & 127;
    const int r = r0 + i;
    float v = 0.f;
    if (r < rcount) {
      if (isG0) v = nf[(size_t)r * 512 + u];
      else {
        const int n = r / 3, kc = r - n * 3;
        v = nf[(size_t)n * 512 + 128 + u * 3 + kc];
      }
    }
    xs[i][u] = f2h(v);
  }
  for (int idx = t; idx < 640; idx += 256) {
    const int i = idx / 10, a = idx - (idx / 10) * 10;
    const int r = r0 + i;
    float v = 0.f;
    if (r < rcount) v = attrs[(size_t)(isG0 ? r : r / 3) * 10 + a];
    at[i][a] = v;
  }
  __syncthreads();

  const int m = lane & 15, q = lane >> 4;
  const int colB = wave * 32;
  const int rr = t >> 2;
  const int off = (t & 3) * 8;

  unsigned int atr2[10];
#pragma unroll
  for (int a = 0; a < 10; ++a) {
    const unsigned int h = f2h(at[rr][a]);
    atr2[a] = h | (h << 16);
  }

  f32x4 acc[4][2];
#pragma unroll
  for (int rt = 0; rt < 4; ++rt)
#pragma unroll
    for (int ct = 0; ct < 2; ++ct) acc[rt][ct] = (f32x4){0.f, 0.f, 0.f, 0.f};

  // prologue: prefetch bfrag for phase 0 (kt = 0, 1)
  f16x8 bf[2][2];
#pragma unroll
  for (int sub = 0; sub < 2; ++sub)
#pragma unroll
    for (int ct = 0; ct < 2; ++ct)
      bf[sub][ct] = *(const f16x8*)&Bsw[(size_t)(sub * 128 + colB + ct * 16 + m) * 32 + q * 8];

#pragma unroll
  for (int a = 0; a < 10; ++a) {
    const unsigned int av2 = atr2[a];
#pragma unroll
    for (int pp = 0; pp < 2; ++pp) {
      const int p = a * 2 + pp;
      const int buf = p & 1;
#pragma unroll
      for (int sub = 0; sub < 2; ++sub) {
        const int kk = 2 * pp + sub;
        const uint4 xv = *(const uint4*)&xs[rr][kk * 32 + off];
        uint4 z;
        z.x = pkmul_h2(xv.x, av2);
        z.y = pkmul_h2(xv.y, av2);
        z.z = pkmul_h2(xv.z, av2);
        z.w = pkmul_h2(xv.w, av2);
        *(uint4*)&zs[buf][sub][rr][off] = z;
      }
      __syncthreads();

      f16x8 bfn[2][2];
      if (p < 19) {
        const int ktn = (p + 1) * 2;
#pragma unroll
        for (int sub = 0; sub < 2; ++sub)
#pragma unroll
          for (int ct = 0; ct < 2; ++ct)
            bfn[sub][ct] = *(const f16x8*)&Bsw[(size_t)((ktn + sub) * 128 + colB + ct * 16 + m) * 32 + q * 8];
      }

#pragma unroll
      for (int sub = 0; sub < 2; ++sub) {
#pragma unroll
        for (int rt = 0; rt < 4; ++rt) {
          const f16x8 afrag = *(const f16x8*)&zs[buf][sub][rt * 16 + m][q * 8];
#pragma unroll
          for (int ct = 0; ct < 2; ++ct)
            acc[rt][ct] = __builtin_amdgcn_mfma_f32_16x16x32_f16(
                afrag, bf[sub][ct], acc[rt][ct], 0, 0, 0);
        }
      }
      bf[0][0] = bfn[0][0]; bf[0][1] = bfn[0][1];
      bf[1][0] = bfn[1][0]; bf[1][1] = bfn[1][1];
    }
  }

#pragma unroll
  for (int rt = 0; rt < 4; ++rt) {
#pragma unroll
    for (int reg = 0; reg < 4; ++reg) {
      const int rloc = rt * 16 + q * 4 + reg;
      const int r = r0 + rloc;
      if (r < rcount) {
#pragma unroll
        for (int ct = 0; ct < 2; ++ct) {
          const int v = colB + ct * 16 + m;
          const float val = acc[rt][ct][reg] * INV_SQRT_CA;
          if (isG0) {
            out_sc[(size_t)r * 512 + v] = val;
          } else {
            const int n = r / 3, kc = r - (r / 3) * 3;
            out_sc[(size_t)n * 512 + 128 + v * 3 + kc] = val;
          }
        }
      }
    }
  }
}

// ---------------------------------------------------------------------------
// Sort-by-receiver: scan -> scatter (perm only, 4B random writes).
// ---------------------------------------------------------------------------
__global__ __launch_bounds__(1024) void k_scan(const int* __restrict__ counts,
                                               int* __restrict__ offsets,
                                               int* __restrict__ cursor) {
  __shared__ int part[1024];
  const int t = threadIdx.x;
  int local[10];
  int s = 0;
#pragma unroll
  for (int i = 0; i < 10; ++i) {
    const int idx = t * 10 + i;
    const int c = (idx < N_NODES) ? counts[idx] : 0;
    local[i] = s;
    s += c;
  }
  part[t] = s;
  __syncthreads();
  for (int off = 1; off < 1024; off <<= 1) {
    const int add = (t >= off) ? part[t - off] : 0;
    __syncthreads();
    part[t] += add;
    __syncthreads();
  }
  const int pre = (t > 0) ? part[t - 1] : 0;
#pragma unroll
  for (int i = 0; i < 10; ++i) {
    const int idx = t * 10 + i;
    if (idx < N_NODES) {
      const int o = pre + local[i];
      offsets[idx] = o;
      cursor[idx] = o;
    }
  }
  if (t == 1023) offsets[N_NODES] = part[1023];
}

__global__ __launch_bounds__(256) void k_scatter(
    const int* __restrict__ eidx, int* __restrict__ cursor,
    int* __restrict__ perm) {
  const int e = blockIdx.x * 256 + threadIdx.x;
  if (e < N_EDGES) {
    const int r = eidx[N_EDGES + e];
    const int pos = atomicAdd(&cursor[r], 1);
    perm[pos] = e;
  }
}

// ---------------------------------------------------------------------------
// K3 (R5-proven core): edge MLP + messages + segmented reduce.
// v7: staging gathers ONE 64B line per edge from pack[] via perm
// (4 threads x float4, all within the line) -> zero over-fetch; R10's
// 3-address 48B gather cost +14MB FETCH and +22us.
// ---------------------------------------------------------------------------
__global__ __launch_bounds__(256, 4) void k_mlp_msg(
    const float* __restrict__ pack, const int* __restrict__ perm,
    const int* __restrict__ offsets,
    const float* __restrict__ R0, const unsigned short* __restrict__ R1a,
    const unsigned short* __restrict__ R2a, const unsigned short* __restrict__ R3a,
    const float* __restrict__ Wd, const __half* __restrict__ Hh,
    float* __restrict__ M, float* __restrict__ density) {
  __shared__ __align__(16) unsigned short actA[128][72];  // 18 KB
  __shared__ __align__(16) unsigned char uni[18432];      // 18 KB union
  __shared__ __align__(16) float ys[128][4];              // 2 KB
  __shared__ __align__(16) int sn[144];                   // 576 B
  __shared__ __align__(16) int rc[128];                   // 512 B
  float (*efs)[9] = (float (*)[9]) & uni[0];
  unsigned short (*actB)[72] = (unsigned short (*)[72]) & uni[0];
  __half (*wls2)[536] = (__half (*)[536]) & uni[0];

  const int t = threadIdx.x;
  const int wave = t >> 6, lane = t & 63, m = lane & 15, q = lane >> 4;
  const int e0 = blockIdx.x * 128;

  // staging: one 64B pack line per edge, 4 threads/edge (float4 each)
#pragma unroll
  for (int it = 0; it < 2; ++it) {
    const int e = it * 64 + (t >> 2), sub = t & 3;
    const int pe = perm[e0 + e];
    const float4 v = ((const float4*)pack)[(size_t)pe * 4 + sub];
    if (sub < 2) {
      const int c0 = sub * 4;
      efs[e][c0] = v.x; efs[e][c0 + 1] = v.y;
      efs[e][c0 + 2] = v.z; efs[e][c0 + 3] = v.w;
    } else if (sub == 2) {
      *(float4*)&ys[e][0] = v;
    } else {
      sn[e] = __builtin_bit_cast(int, v.x);
      rc[e] = __builtin_bit_cast(int, v.y);
    }
  }
  if (t >= 128 && t < 144) sn[t] = 0;  // pad: tail refill reads sn[128..143]
  __syncthreads();

  const int u = t & 127, half = t >> 7;
  const size_t ucol = (size_t)(u << 2);
  uint2 hA[4], hB[4];
#pragma unroll
  for (int j = 0; j < 4; ++j)
    hA[j] = *(const uint2*)&Hh[(size_t)sn[j] * 512 + ucol];
#pragma unroll
  for (int j = 0; j < 4; ++j)
    hB[j] = *(const uint2*)&Hh[(size_t)sn[4 + j] * 512 + ucol];

  if (t < 128) {
    float s = 0.f;
#pragma unroll
    for (int i = 0; i < 8; ++i) s = fmaf(efs[t][i], Wd[i], s);
    s *= INV_SQRT_R;
    atomic_add_f32(&density[rc[t]], tanhf(s * s));
  }

  // L1
  {
    const int e = t & 127, j0 = (t >> 7) * 32;
    float a[32] = {};
#pragma unroll
    for (int i = 0; i < 8; ++i) {
      const float v = efs[e][i];
#pragma unroll
      for (int jj = 0; jj < 32; ++jj)
        a[jj] = fmaf(v, R0[i * 64 + j0 + jj], a[jj]);
    }
#pragma unroll
    for (int g = 0; g < 8; ++g) {
      uint2 pk;
      pk.x = pk2h(silu_f(a[4 * g] * INV_SQRT_R), silu_f(a[4 * g + 1] * INV_SQRT_R));
      pk.y = pk2h(silu_f(a[4 * g + 2] * INV_SQRT_R), silu_f(a[4 * g + 3] * INV_SQRT_R));
      *(uint2*)&actA[e][j0 + g * 4] = pk;
    }
  }
  __syncthreads();

  // L2
  {
    const f16x8 af0 = *(const f16x8*)&R1a[(((wave * 16 + m) * 2 + 0) << 5) + q * 8];
    const f16x8 af1 = *(const f16x8*)&R1a[(((wave * 16 + m) * 2 + 1) << 5) + q * 8];
#pragma unroll
    for (int et = 0; et < 8; ++et) {
      const f16x8 bf0 = *(const f16x8*)&actA[et * 16 + m][q * 8];
      const f16x8 bf1 = *(const f16x8*)&actA[et * 16 + m][32 + q * 8];
      f32x4 c = {0.f, 0.f, 0.f, 0.f};
      c = __builtin_amdgcn_mfma_f32_16x16x32_f16(af0, bf0, c, 0, 0, 0);
      c = __builtin_amdgcn_mfma_f32_16x16x32_f16(af1, bf1, c, 0, 0, 0);
      uint2 pk;
      pk.x = pk2h(silu_f(c[0] * INV_SQRT_64), silu_f(c[1] * INV_SQRT_64));
      pk.y = pk2h(silu_f(c[2] * INV_SQRT_64), silu_f(c[3] * INV_SQRT_64));
      *(uint2*)&actB[et * 16 + m][wave * 16 + q * 4] = pk;
    }
  }
  __syncthreads();

  // L3
  {
    const f16x8 af0 = *(const f16x8*)&R2a[(((wave * 16 + m) * 2 + 0) << 5) + q * 8];
    const f16x8 af1 = *(const f16x8*)&R2a[(((wave * 16 + m) * 2 + 1) << 5) + q * 8];
#pragma unroll
    for (int et = 0; et < 8; ++et) {
      const f16x8 bf0 = *(const f16x8*)&actB[et * 16 + m][q * 8];
      const f16x8 bf1 = *(const f16x8*)&actB[et * 16 + m][32 + q * 8];
      f32x4 c = {0.f, 0.f, 0.f, 0.f};
      c = __builtin_amdgcn_mfma_f32_16x16x32_f16(af0, bf0, c, 0, 0, 0);
      c = __builtin_amdgcn_mfma_f32_16x16x32_f16(af1, bf1, c, 0, 0, 0);
      uint2 pk;
      pk.x = pk2h(silu_f(c[0] * INV_SQRT_64), silu_f(c[1] * INV_SQRT_64));
      pk.y = pk2h(silu_f(c[2] * INV_SQRT_64), silu_f(c[3] * INV_SQRT_64));
      *(uint2*)&actA[et * 16 + m][wave * 16 + q * 4] = pk;
    }
  }
  __syncthreads();

  const int baseJ = (wave & 1) * 4 + (wave >> 1) * 16;
  f16x8 afL[4][2], afH[4][2];
#pragma unroll
  for (int i = 0; i < 4; ++i) {
#pragma unroll
    for (int kt = 0; kt < 2; ++kt) {
      const int JL = baseJ + i, JH = JL + 8;
      afL[i][kt] = *(const f16x8*)&R3a[(((JL * 16 + m) * 2 + kt) << 5) + q * 8];
      afH[i][kt] = *(const f16x8*)&R3a[(((JH * 16 + m) * 2 + kt) << 5) + q * 8];
    }
  }

  float a0 = 0.f, a1 = 0.f, a2 = 0.f, a3 = 0.f;
  int cur = rc[0];
  int s0c = offsets[cur], s1c = offsets[cur + 1];
  const int colx = (half ? 128 + u : u) * 2;

  auto flush = [&](int n, int s0, int s1) {
    float* Mp = &M[(size_t)n * 1024 + (half << 9) + (u << 2)];
    if (s0 >= e0 && s1 <= e0 + 128) {
      *(float4*)Mp = make_float4(a0, a1, a2, a3);
    } else {
      atomic_add_f32(Mp + 0, a0);
      atomic_add_f32(Mp + 1, a1);
      atomic_add_f32(Mp + 2, a2);
      atomic_add_f32(Mp + 3, a3);
    }
  };

  auto proc = [&](const uint2 hcur, unsigned int pr, const float4 yv, int n) {
    if (n != cur) {  // wave-uniform
      flush(cur, s0c, s1c);
      a0 = a1 = a2 = a3 = 0.f;
      cur = n;
      s0c = offsets[n];
      s1c = offsets[n + 1];
    }
    const float4 h4 = h4tof4(hcur);
    const __half2 ph = __builtin_bit_cast(__half2, pr);
    const float2 pw = __half22float2(ph);
    if (half == 0) {
      a0 = fmaf(pw.x * h4.x, yv.x, a0);
      const float c1 = pw.y * h4.x;
      a1 = fmaf(c1, yv.y, a1);
      a2 = fmaf(c1, yv.z, a2);
      a3 = fmaf(c1, yv.w, a3);
    } else {
      const float dt = h4.y * yv.y + h4.z * yv.z + h4.w * yv.w;
      a0 = fmaf(pw.y * dt, INV_SQRT_3, a0);
      const float c3 = pw.x * yv.x;
      a1 = fmaf(c3, h4.y, a1);
      a2 = fmaf(c3, h4.z, a2);
      a3 = fmaf(c3, h4.w, a3);
    }
  };

#define MSG_GROUP(G, HX)                                                    \
  {                                                                         \
    const int gb = ch * 16 + (G) * 4;                                       \
    unsigned int prv[4];                                                    \
    float4 yv4[4];                                                          \
    _Pragma("unroll") for (int j = 0; j < 4; ++j)                           \
        prv[j] = *(const unsigned int*)&wls2[(G) * 4 + j][colx];            \
    _Pragma("unroll") for (int j = 0; j < 4; ++j)                           \
        yv4[j] = *(const float4*)&ys[gb + j][0];                            \
    const int4 rc4 = *(const int4*)&rc[gb];                                 \
    proc(HX[0], prv[0], yv4[0], rc4.x);                                     \
    proc(HX[1], prv[1], yv4[1], rc4.y);                                     \
    proc(HX[2], prv[2], yv4[2], rc4.z);                                     \
    proc(HX[3], prv[3], yv4[3], rc4.w);                                     \
    const int4 sn4 = *(const int4*)&sn[gb + 8];                             \
    HX[0] = *(const uint2*)&Hh[(size_t)sn4.x * 512 + ucol];                 \
    HX[1] = *(const uint2*)&Hh[(size_t)sn4.y * 512 + ucol];                 \
    HX[2] = *(const uint2*)&Hh[(size_t)sn4.z * 512 + ucol];                 \
    HX[3] = *(const uint2*)&Hh[(size_t)sn4.w * 512 + ucol];                 \
  }

  // BARRIER-FREE chunk loop (wave w produces AND consumes wls2 [w*64,(w+1)*64))
#pragma unroll 1
  for (int ch = 0; ch < 8; ++ch) {
    {
      const f16x8 bf0 = *(const f16x8*)&actA[ch * 16 + m][q * 8];
      const f16x8 bf1 = *(const f16x8*)&actA[ch * 16 + m][32 + q * 8];
#pragma unroll
      for (int i = 0; i < 4; ++i) {
        f32x4 cL = {0.f, 0.f, 0.f, 0.f}, cH = {0.f, 0.f, 0.f, 0.f};
        cL = __builtin_amdgcn_mfma_f32_16x16x32_f16(afL[i][0], bf0, cL, 0, 0, 0);
        cL = __builtin_amdgcn_mfma_f32_16x16x32_f16(afL[i][1], bf1, cL, 0, 0, 0);
        cH = __builtin_amdgcn_mfma_f32_16x16x32_f16(afH[i][0], bf0, cH, 0, 0, 0);
        cH = __builtin_amdgcn_mfma_f32_16x16x32_f16(afH[i][1], bf1, cH, 0, 0, 0);
        uint4 pk;
        pk.x = pk2h(cL[0] * INV_SQRT_64, cH[0] * INV_SQRT_64);
        pk.y = pk2h(cL[1] * INV_SQRT_64, cH[1] * INV_SQRT_64);
        pk.z = pk2h(cL[2] * INV_SQRT_64, cH[2] * INV_SQRT_64);
        pk.w = pk2h(cL[3] * INV_SQRT_64, cH[3] * INV_SQRT_64);
        const int JL = baseJ + i;
        const int pidx0 = ((JL < 8) ? JL * 16 : (JL - 16) * 16 + 128) + q * 4;
        *(uint4*)&wls2[m][pidx0 * 2] = pk;
      }
    }
    MSG_GROUP(0, hA)
    MSG_GROUP(1, hB)
    MSG_GROUP(2, hA)
    MSG_GROUP(3, hB)
  }
#undef MSG_GROUP
  flush(cur, s0c, s1c);
}

// ---------------------------------------------------------------------------
// k_out_mfma (R9-proven): out = M@Wl via f16 MFMA.
// ---------------------------------------------------------------------------
__global__ __launch_bounds__(256) void k_out_mfma(
    const float* __restrict__ M, const float* __restrict__ density,
    const unsigned short* __restrict__ Wla0,
    const unsigned short* __restrict__ Wla1, float* __restrict__ out) {
  __shared__ __align__(16) unsigned char sm[64 * 264 * 2];  // 33792 B union
  __shared__ float dens[16];
  unsigned short (*xso)[264] = (unsigned short (*)[264])sm;  // [64][264] f16
  float (*ost)[512] = (float (*)[512])sm;                    // 32768 B
  const int t = threadIdx.x;
  const int wave = t >> 6, lane = t & 63, m = lane & 15, q = lane >> 4;
  const int n0 = blockIdx.x * 16;

  if (t < 16) dens[t] = INV_SQRT_2C / (density[n0 + t] + 1.0f);

  const float4* Mf4 = (const float4*)&M[(size_t)n0 * 1024];
  for (int i = t; i < 4096; i += 256) {
    const float4 v = Mf4[i];
    const int nn = i >> 8, p = i & 255;
    xso[nn][p] = f2h(v.x);
    const int rb = 16 + nn * 3;
    xso[rb][p] = f2h(v.y);
    xso[rb + 1][p] = f2h(v.z);
    xso[rb + 2][p] = f2h(v.w);
  }
  __syncthreads();

  const int colB = wave * 32;
  f32x4 acc[4][2];
#pragma unroll
  for (int rt = 0; rt < 4; ++rt)
#pragma unroll
    for (int ct = 0; ct < 2; ++ct) acc[rt][ct] = (f32x4){0.f, 0.f, 0.f, 0.f};

#pragma unroll
  for (int kt = 0; kt < 8; ++kt) {
    f16x8 bf0[2], bf1[2];
#pragma unroll
    for (int ct = 0; ct < 2; ++ct) {
      const int col = colB + ct * 16 + m;
      bf0[ct] = *(const f16x8*)&Wla0[((col * 8 + kt) << 5) + q * 8];
      bf1[ct] = *(const f16x8*)&Wla1[((col * 8 + kt) << 5) + q * 8];
    }
#pragma unroll
    for (int rt = 0; rt < 4; ++rt) {
      const f16x8 af = *(const f16x8*)&xso[rt * 16 + m][kt * 32 + q * 8];
#pragma unroll
      for (int ct = 0; ct < 2; ++ct)
        acc[rt][ct] = __builtin_amdgcn_mfma_f32_16x16x32_f16(
            af, rt == 0 ? bf0[ct] : bf1[ct], acc[rt][ct], 0, 0, 0);
    }
  }
  __syncthreads();  // all xso reads done before ost (alias) is written

#pragma unroll
  for (int rt = 0; rt < 4; ++rt) {
#pragma unroll
    for (int reg = 0; reg < 4; ++reg) {
      const int rloc = rt * 16 + q * 4 + reg;
#pragma unroll
      for (int ct = 0; ct < 2; ++ct) {
        const int v = colB + ct * 16 + m;
        if (rt == 0) {
          ost[rloc][v * 4] = acc[rt][ct][reg] * dens[rloc];
        } else {
          const int rr = rloc - 16;
          const int nn = rr / 3, kc = rr - nn * 3;
          ost[nn][v * 4 + 1 + kc] = acc[rt][ct][reg] * dens[nn];
        }
      }
    }
  }
  __syncthreads();
  for (int i = t; i < 2048; i += 256) {
    const int nn = i >> 7, pos = i & 127;
    *(float4*)&out[(size_t)(n0 + nn) * 512 + pos * 4] =
        *(const float4*)&ost[nn][pos * 4];
  }
}

// ---------------------------------------------------------------------------
extern "C" void kernel_launch(void* const* d_in, const int* in_sizes, int n_in,
                              void* d_out, int out_size, void* d_ws, size_t ws_size,
                              hipStream_t stream) {
  const float* node_attrs = (const float*)d_in[0];
  const float* node_feats = (const float*)d_in[1];
  const float* edge_attrs = (const float*)d_in[2];
  const float* edge_feats = (const float*)d_in[3];
  const int*   edge_index = (const int*)d_in[4];
  const float* W_up0 = (const float*)d_in[5];
  const float* W_up1 = (const float*)d_in[6];
  const float* R0 = (const float*)d_in[7];
  const float* R1 = (const float*)d_in[8];
  const float* R2 = (const float*)d_in[9];
  const float* R3 = (const float*)d_in[10];
  const float* Wd  = (const float*)d_in[11];
  const float* Wl0 = (const float*)d_in[12];
  const float* Wl1 = (const float*)d_in[13];
  const float* Ws0 = (const float*)d_in[14];
  const float* Ws1 = (const float*)d_in[15];
  float* out = (float*)d_out;

  // Workspace: H | M | density | counts | offsets | cursor | perm |
  // Bsw0 | Bsw1 | R1a | R2a | R3a | Wua0 | Wua1 | Wla0 | Wla1 | pack
  __half* Hh = (__half*)d_ws;
  float* M = (float*)d_ws + (size_t)N_NODES * 512;
  float* density = M + (size_t)N_NODES * 1024;
  int* counts  = (int*)(density + 10000);
  int* offsets = counts + 10016;
  int* cursor  = offsets + 10016;
  int* perm    = cursor + 10016;
  unsigned short* Bsw0 = (unsigned short*)(perm + N_EDGES);
  unsigned short* Bsw1 = Bsw0 + 1280 * 128;
  unsigned short* R1a  = Bsw1 + 1280 * 128;
  unsigned short* R2a  = R1a + 64 * 64;
  unsigned short* R3a  = R2a + 64 * 64;
  unsigned short* Wua0 = R3a + 64 * 512;
  unsigned short* Wua1 = Wua0 + 128 * 128;
  unsigned short* Wla0 = Wua1 + 128 * 128;
  unsigned short* Wla1 = Wla0 + 256 * 128;
  // 64B-align the pack array (base of d_ws is page-aligned; offset is in
  // ushorts -> ensure multiple of 32 ushorts = 64B)
  float* pack = (float*)(Wla1 + 256 * 128);

  hipMemsetAsync(M, 0, ((size_t)N_NODES * 1024 + 10000 + 10016) * sizeof(float),
                 stream);

  k_prep<<<1592, 256, 0, stream>>>(Ws0, Ws1, Bsw0, Bsw1, R1, R1a, R2, R2a, R3,
                                   R3a, W_up0, Wua0, W_up1, Wua1, Wl0, Wla0,
                                   Wl1, Wla1, edge_feats, edge_attrs,
                                   edge_index, pack, counts);
  k_node_mfma<<<N_NODES / 16, 256, 0, stream>>>(node_feats, Wua0, Wua1, Hh);
  k_scan<<<1, 1024, 0, stream>>>(counts, offsets, cursor);
  k_scatter<<<(N_EDGES + 255) / 256, 256, 0, stream>>>(edge_index, cursor,
                                                       perm);
  k_mlp_msg<<<N_EDGES / 128, 256, 0, stream>>>(pack, perm, offsets, R0, R1a,
                                               R2a, R3a, Wd, Hh, M, density);
  k_out_mfma<<<N_NODES / 16, 256, 0, stream>>>(M, density, Wla0, Wla1, out);
  k_skip_mfma<<<157 + 469, 256, 0, stream>>>(node_feats, node_attrs, Bsw0, Bsw1,
                                             out + (size_t)N_NODES * 512);
}